// Round 1
// baseline (1237.192 us; speedup 1.0000x reference)
//
#include <hip/hip_runtime.h>
#include <hip/hip_bf16.h>

// Problem constants
#define T_SEQ 1024
#define U_DIM 512
#define DH 64
#define NHEAD 8
#define NBATCH 8
#define MAXD 16
#define LN_EPS 1e-3f

// ---------------------------------------------------------------------------
// GEMM: out[8192,512] = act(A[8192,512] @ W[512,512] + bias) (+ resid)
// BM=64, BN=128, BK=16, 256 threads, 4x8 microtile.
// ---------------------------------------------------------------------------
template <int RESID>
__global__ __launch_bounds__(256) void gemm512(const float* __restrict__ A,
                                               const float* __restrict__ W,
                                               const float* __restrict__ bias,
                                               const float* __restrict__ resid,
                                               float* __restrict__ out) {
    __shared__ float As[64][17];      // +1 pad: conflict-free scalar reads
    __shared__ float4 Ws4[16][32];    // 16 k-rows x 128 cols (as float4)

    const int tid = threadIdx.x;
    const int row0 = blockIdx.x * 64;
    const int col0 = blockIdx.y * 128;
    const int tx = tid & 15;   // col group: cols col0 + tx*8 .. +7
    const int ty = tid >> 4;   // row group: rows row0 + ty*4 .. +3

    float acc[4][8];
#pragma unroll
    for (int i = 0; i < 4; ++i)
#pragma unroll
        for (int j = 0; j < 8; ++j) acc[i][j] = 0.f;

    const int lr = tid >> 2, lc = tid & 3;   // A-tile load: row lr, float4 col lc
    const int wr = tid >> 4, wc = tid & 15;  // W-tile load

    for (int kk = 0; kk < 512; kk += 16) {
        float4 av = *(const float4*)&A[(size_t)(row0 + lr) * 512 + kk + lc * 4];
        As[lr][lc * 4 + 0] = av.x;
        As[lr][lc * 4 + 1] = av.y;
        As[lr][lc * 4 + 2] = av.z;
        As[lr][lc * 4 + 3] = av.w;
        Ws4[wr][wc]      = *(const float4*)&W[(size_t)(kk + wr) * 512 + col0 + wc * 4];
        Ws4[wr][wc + 16] = *(const float4*)&W[(size_t)(kk + wr) * 512 + col0 + 64 + wc * 4];
        __syncthreads();
#pragma unroll
        for (int k = 0; k < 16; ++k) {
            float a0 = As[ty * 4 + 0][k];
            float a1 = As[ty * 4 + 1][k];
            float a2 = As[ty * 4 + 2][k];
            float a3 = As[ty * 4 + 3][k];
            float4 b0 = Ws4[k][tx * 2];
            float4 b1 = Ws4[k][tx * 2 + 1];
            acc[0][0] += a0 * b0.x; acc[0][1] += a0 * b0.y; acc[0][2] += a0 * b0.z; acc[0][3] += a0 * b0.w;
            acc[0][4] += a0 * b1.x; acc[0][5] += a0 * b1.y; acc[0][6] += a0 * b1.z; acc[0][7] += a0 * b1.w;
            acc[1][0] += a1 * b0.x; acc[1][1] += a1 * b0.y; acc[1][2] += a1 * b0.z; acc[1][3] += a1 * b0.w;
            acc[1][4] += a1 * b1.x; acc[1][5] += a1 * b1.y; acc[1][6] += a1 * b1.z; acc[1][7] += a1 * b1.w;
            acc[2][0] += a2 * b0.x; acc[2][1] += a2 * b0.y; acc[2][2] += a2 * b0.z; acc[2][3] += a2 * b0.w;
            acc[2][4] += a2 * b1.x; acc[2][5] += a2 * b1.y; acc[2][6] += a2 * b1.z; acc[2][7] += a2 * b1.w;
            acc[3][0] += a3 * b0.x; acc[3][1] += a3 * b0.y; acc[3][2] += a3 * b0.z; acc[3][3] += a3 * b0.w;
            acc[3][4] += a3 * b1.x; acc[3][5] += a3 * b1.y; acc[3][6] += a3 * b1.z; acc[3][7] += a3 * b1.w;
        }
        __syncthreads();
    }

#pragma unroll
    for (int i = 0; i < 4; ++i) {
        const int rrow = row0 + ty * 4 + i;
        const int cbase = col0 + tx * 8;
        float vals[8];
#pragma unroll
        for (int j = 0; j < 8; ++j) {
            float v = acc[i][j] + bias[cbase + j];
            v = fmaxf(v, 0.f);
            if (RESID) v += resid[(size_t)rrow * 512 + cbase + j];
            vals[j] = v;
        }
        float4* dst = (float4*)&out[(size_t)rrow * 512 + cbase];
        dst[0] = make_float4(vals[0], vals[1], vals[2], vals[3]);
        dst[1] = make_float4(vals[4], vals[5], vals[6], vals[7]);
    }
}

// ---------------------------------------------------------------------------
// Flash-style causal attention with relative position (k and v tables).
// Grid: (16 q-tiles, 64 head-batches). Block: 256 threads.
// BQ=64 q rows, BS=32 s cols per iteration.
// thread: r = tid>>2 (row), q4 = tid&3 (s-slice q4*8..+7, d-slice q4*16..+15)
// ---------------------------------------------------------------------------
__global__ __launch_bounds__(256) void attn_kernel(const float* __restrict__ qe,
                                                   const float* __restrict__ ke,
                                                   const float* __restrict__ ve,
                                                   const float* __restrict__ pe_k,
                                                   const float* __restrict__ pe_v,
                                                   float* __restrict__ ao) {
    __shared__ float Qs[64][72];
    __shared__ float Ks[32][72];
    __shared__ float Vs[32][72];
    __shared__ float Ss[64][33];
    __shared__ float qpe[64][17];
    __shared__ float wsumS[64][17];
    __shared__ float pek[17][64];
    __shared__ float pev[17][64];
    __shared__ float redmax[64][4];
    __shared__ float redsum[64][4];
    __shared__ float m_arr[64];
    __shared__ float l_arr[64];

    const int tid = threadIdx.x;
    const int qt = 15 - blockIdx.x;   // heavy tiles first (load balance)
    const int hb = blockIdx.y;
    const int h = hb >> 3;
    const int b = hb & 7;
    const int t0 = qt * 64;

    const int r = tid >> 2;
    const int q4 = tid & 3;

    // Load Q tile (each thread: 16 contiguous floats of one row)
    {
        const int lr = tid >> 2;
        const int lc = (tid & 3) * 16;
        const float* src = &qe[(size_t)(b * T_SEQ + (t0 + lr)) * U_DIM + h * DH + lc];
        float4* dst = (float4*)&Qs[lr][lc];
#pragma unroll
        for (int i = 0; i < 4; ++i) dst[i] = ((const float4*)src)[i];
    }
    // pe tables (only rows 0..16 reachable under causal mask)
    for (int i = tid; i < 17 * 64; i += 256) {
        pek[i >> 6][i & 63] = pe_k[i];
        pev[i >> 6][i & 63] = pe_v[i];
    }
    if (tid < 64) { m_arr[tid] = -3.0e38f; l_arr[tid] = 0.f; }
    for (int i = tid; i < 64 * 17; i += 256) wsumS[i / 17][i % 17] = 0.f;
    __syncthreads();

    // qpe[r][ri] = Q[r] . pe_k[ri]
    for (int i = tid; i < 64 * 17; i += 256) {
        const int rr = i / 17, ri = i % 17;
        float a = 0.f;
        for (int k = 0; k < 64; ++k) a += Qs[rr][k] * pek[ri][k];
        qpe[rr][ri] = a;
    }

    float oacc[16];
#pragma unroll
    for (int i = 0; i < 16; ++i) oacc[i] = 0.f;

    const int tg = t0 + r;
    const int smax = t0 + 63;

    for (int s0 = 0; s0 <= smax; s0 += 32) {
        __syncthreads();  // protect Ks/Vs/Ss from previous iteration readers
        {
            const int lr2 = tid >> 3;
            const int lc2 = (tid & 7) * 8;
            const size_t gb = (size_t)(b * T_SEQ + (s0 + lr2)) * U_DIM + h * DH + lc2;
            *(float4*)&Ks[lr2][lc2]     = *(const float4*)&ke[gb];
            *(float4*)&Ks[lr2][lc2 + 4] = *(const float4*)&ke[gb + 4];
            *(float4*)&Vs[lr2][lc2]     = *(const float4*)&ve[gb];
            *(float4*)&Vs[lr2][lc2 + 4] = *(const float4*)&ve[gb + 4];
        }
        __syncthreads();

        // scores: 8 per thread
        float dotv[8];
#pragma unroll
        for (int j = 0; j < 8; ++j) dotv[j] = 0.f;
#pragma unroll 4
        for (int k4 = 0; k4 < 16; ++k4) {
            float4 qv = *(const float4*)&Qs[r][k4 * 4];
#pragma unroll
            for (int j = 0; j < 8; ++j) {
                float4 kv = *(const float4*)&Ks[q4 * 8 + j][k4 * 4];
                dotv[j] += qv.x * kv.x + qv.y * kv.y + qv.z * kv.z + qv.w * kv.w;
            }
        }
        float sc[8];
        float lmax = -3.0e38f;
#pragma unroll
        for (int j = 0; j < 8; ++j) {
            const int sg = s0 + q4 * 8 + j;
            const int dlt = sg - tg;
            if (dlt <= 0) {
                const int ri = (dlt < -MAXD) ? 0 : (dlt + MAXD);
                sc[j] = (dotv[j] + qpe[r][ri]) * 0.125f;
                lmax = fmaxf(lmax, sc[j]);
            } else {
                sc[j] = -3.0e38f;
            }
        }
        redmax[r][q4] = lmax;
        __syncthreads();

        const float m_old = m_arr[r];
        const float tmax = fmaxf(fmaxf(redmax[r][0], redmax[r][1]),
                                 fmaxf(redmax[r][2], redmax[r][3]));
        const float m_new = fmaxf(m_old, tmax);
        const float alpha = __expf(m_old - m_new);

        float psum = 0.f;
#pragma unroll
        for (int j = 0; j < 8; ++j) {
            const int sg = s0 + q4 * 8 + j;
            const float p = (sg <= tg) ? __expf(sc[j] - m_new) : 0.f;
            Ss[r][q4 * 8 + j] = p;
            psum += p;
        }
        redsum[r][q4] = psum;
        __syncthreads();

        if (q4 == 0) {
            const float ls = redsum[r][0] + redsum[r][1] + redsum[r][2] + redsum[r][3];
            l_arr[r] = l_arr[r] * alpha + ls;
            m_arr[r] = m_new;
#pragma unroll
            for (int ri = 0; ri < 17; ++ri) wsumS[r][ri] *= alpha;
            for (int s = 0; s < 32; ++s) {
                const int sg = s0 + s;
                const int dlt = sg - tg;
                if (dlt <= 0) {
                    const int ri = (dlt < -MAXD) ? 0 : (dlt + MAXD);
                    wsumS[r][ri] += Ss[r][s];
                }
            }
        }

        // O update
#pragma unroll
        for (int i = 0; i < 16; ++i) oacc[i] *= alpha;
#pragma unroll 4
        for (int s = 0; s < 32; ++s) {
            const float p = Ss[r][s];
            const float4* vrow = (const float4*)&Vs[s][q4 * 16];
#pragma unroll
            for (int i4 = 0; i4 < 4; ++i4) {
                const float4 vv = vrow[i4];
                oacc[i4 * 4 + 0] += p * vv.x;
                oacc[i4 * 4 + 1] += p * vv.y;
                oacc[i4 * 4 + 2] += p * vv.z;
                oacc[i4 * 4 + 3] += p * vv.w;
            }
        }
    }
    __syncthreads();  // wsumS / l_arr final

    const float inv = 1.0f / l_arr[r];
    float outv[16];
#pragma unroll
    for (int i = 0; i < 16; ++i) outv[i] = oacc[i];
    for (int ri = 0; ri < 17; ++ri) {
        const float wv = wsumS[r][ri];
        const float* pr = &pev[ri][q4 * 16];
#pragma unroll
        for (int i = 0; i < 16; ++i) outv[i] += wv * pr[i];
    }
    float* dst = &ao[(size_t)(b * T_SEQ + tg) * U_DIM + h * DH + q4 * 16];
#pragma unroll
    for (int i = 0; i < 16; ++i) dst[i] = outv[i] * inv;
}

// ---------------------------------------------------------------------------
// Row LayerNorm (in-place on [8192, 512]): two-pass mean/var, eps=1e-3
// ---------------------------------------------------------------------------
__global__ __launch_bounds__(256) void ln_kernel(float* __restrict__ io,
                                                 const float* __restrict__ gamma,
                                                 const float* __restrict__ beta) {
    const int row = blockIdx.x;
    const int tid = threadIdx.x;
    float* rp = &io[(size_t)row * 512];
    float2 v = *(float2*)&rp[tid * 2];

    float s = v.x + v.y;
#pragma unroll
    for (int off = 32; off > 0; off >>= 1) s += __shfl_down(s, off);

    __shared__ float red[4];
    __shared__ float bc[2];
    const int wid = tid >> 6, lane = tid & 63;
    if (lane == 0) red[wid] = s;
    __syncthreads();
    if (tid == 0) bc[0] = (red[0] + red[1] + red[2] + red[3]) * (1.0f / 512.0f);
    __syncthreads();
    const float mu = bc[0];

    const float d0 = v.x - mu, d1 = v.y - mu;
    float sq = d0 * d0 + d1 * d1;
#pragma unroll
    for (int off = 32; off > 0; off >>= 1) sq += __shfl_down(sq, off);
    if (lane == 0) red[wid] = sq;
    __syncthreads();
    if (tid == 0)
        bc[1] = rsqrtf((red[0] + red[1] + red[2] + red[3]) * (1.0f / 512.0f) + LN_EPS);
    __syncthreads();
    const float rs = bc[1];

    const int c = tid * 2;
    float2 o;
    o.x = d0 * rs * gamma[c] + beta[c];
    o.y = d1 * rs * gamma[c + 1] + beta[c + 1];
    *(float2*)&rp[c] = o;
}

// ---------------------------------------------------------------------------
extern "C" void kernel_launch(void* const* d_in, const int* in_sizes, int n_in,
                              void* d_out, int out_size, void* d_ws, size_t ws_size,
                              hipStream_t stream) {
    const float* q     = (const float*)d_in[0];
    const float* k     = (const float*)d_in[1];
    const float* v     = (const float*)d_in[2];
    const float* Wq    = (const float*)d_in[3];
    const float* bq    = (const float*)d_in[4];
    const float* Wk    = (const float*)d_in[5];
    const float* bk    = (const float*)d_in[6];
    const float* Wv    = (const float*)d_in[7];
    const float* bv    = (const float*)d_in[8];
    const float* Wo    = (const float*)d_in[9];
    const float* bo    = (const float*)d_in[10];
    const float* gamma = (const float*)d_in[11];
    const float* beta  = (const float*)d_in[12];
    const float* pe_k  = (const float*)d_in[13];
    const float* pe_v  = (const float*)d_in[14];
    float* out = (float*)d_out;

    const size_t SZ = (size_t)NBATCH * T_SEQ * U_DIM;  // 4,194,304 floats
    float* qe = (float*)d_ws;
    float* ke = qe + SZ;
    float* ve = ke + SZ;
    float* ao = ve + SZ;

    dim3 gg(128, 4), bb(256);
    gemm512<0><<<gg, bb, 0, stream>>>(q, Wq, bq, nullptr, qe);
    gemm512<0><<<gg, bb, 0, stream>>>(k, Wk, bk, nullptr, ke);
    gemm512<0><<<gg, bb, 0, stream>>>(v, Wv, bv, nullptr, ve);
    attn_kernel<<<dim3(16, 64), bb, 0, stream>>>(qe, ke, ve, pe_k, pe_v, ao);
    gemm512<1><<<gg, bb, 0, stream>>>(ao, Wo, bo, q, out);
    ln_kernel<<<dim3(8192), bb, 0, stream>>>(out, gamma, beta);
}

// Round 2
// 468.602 us; speedup vs baseline: 2.6402x; 2.6402x over previous
//
#include <hip/hip_runtime.h>
#include <hip/hip_bf16.h>

// Problem constants
#define T_SEQ 1024
#define U_DIM 512
#define LN_EPS 1e-3f

typedef float  f32x4  __attribute__((ext_vector_type(4)));
typedef short  bf16x8 __attribute__((ext_vector_type(8)));

__device__ __forceinline__ unsigned short f2bf(float f) {
    union { float f; unsigned u; } x; x.f = f;
    unsigned r = x.u + 0x7fffu + ((x.u >> 16) & 1u);   // RNE
    return (unsigned short)(r >> 16);
}
__device__ __forceinline__ int packbf(float a, float b) {
    return (int)((unsigned)f2bf(a) | ((unsigned)f2bf(b) << 16));
}

// ---------------------------------------------------------------------------
// GEMM: out[8192,512] = relu(A[8192,512] @ W[512,512] + bias) (+ resid)
// (unchanged from round 1 — converted to MFMA next round)
// ---------------------------------------------------------------------------
template <int RESID>
__global__ __launch_bounds__(256) void gemm512(const float* __restrict__ A,
                                               const float* __restrict__ W,
                                               const float* __restrict__ bias,
                                               const float* __restrict__ resid,
                                               float* __restrict__ out) {
    __shared__ float As[64][17];
    __shared__ float4 Ws4[16][32];

    const int tid = threadIdx.x;
    const int row0 = blockIdx.x * 64;
    const int col0 = blockIdx.y * 128;
    const int tx = tid & 15;
    const int ty = tid >> 4;

    float acc[4][8];
#pragma unroll
    for (int i = 0; i < 4; ++i)
#pragma unroll
        for (int j = 0; j < 8; ++j) acc[i][j] = 0.f;

    const int lr = tid >> 2, lc = tid & 3;
    const int wr = tid >> 4, wc = tid & 15;

    for (int kk = 0; kk < 512; kk += 16) {
        float4 av = *(const float4*)&A[(size_t)(row0 + lr) * 512 + kk + lc * 4];
        As[lr][lc * 4 + 0] = av.x;
        As[lr][lc * 4 + 1] = av.y;
        As[lr][lc * 4 + 2] = av.z;
        As[lr][lc * 4 + 3] = av.w;
        Ws4[wr][wc]      = *(const float4*)&W[(size_t)(kk + wr) * 512 + col0 + wc * 4];
        Ws4[wr][wc + 16] = *(const float4*)&W[(size_t)(kk + wr) * 512 + col0 + 64 + wc * 4];
        __syncthreads();
#pragma unroll
        for (int k = 0; k < 16; ++k) {
            float a0 = As[ty * 4 + 0][k];
            float a1 = As[ty * 4 + 1][k];
            float a2 = As[ty * 4 + 2][k];
            float a3 = As[ty * 4 + 3][k];
            float4 b0 = Ws4[k][tx * 2];
            float4 b1 = Ws4[k][tx * 2 + 1];
            acc[0][0] += a0 * b0.x; acc[0][1] += a0 * b0.y; acc[0][2] += a0 * b0.z; acc[0][3] += a0 * b0.w;
            acc[0][4] += a0 * b1.x; acc[0][5] += a0 * b1.y; acc[0][6] += a0 * b1.z; acc[0][7] += a0 * b1.w;
            acc[1][0] += a1 * b0.x; acc[1][1] += a1 * b0.y; acc[1][2] += a1 * b0.z; acc[1][3] += a1 * b0.w;
            acc[1][4] += a1 * b1.x; acc[1][5] += a1 * b1.y; acc[1][6] += a1 * b1.z; acc[1][7] += a1 * b1.w;
            acc[2][0] += a2 * b0.x; acc[2][1] += a2 * b0.y; acc[2][2] += a2 * b0.z; acc[2][3] += a2 * b0.w;
            acc[2][4] += a2 * b1.x; acc[2][5] += a2 * b1.y; acc[2][6] += a2 * b1.z; acc[2][7] += a2 * b1.w;
            acc[3][0] += a3 * b0.x; acc[3][1] += a3 * b0.y; acc[3][2] += a3 * b0.z; acc[3][3] += a3 * b0.w;
            acc[3][4] += a3 * b1.x; acc[3][5] += a3 * b1.y; acc[3][6] += a3 * b1.z; acc[3][7] += a3 * b1.w;
        }
        __syncthreads();
    }

#pragma unroll
    for (int i = 0; i < 4; ++i) {
        const int rrow = row0 + ty * 4 + i;
        const int cbase = col0 + tx * 8;
        float vals[8];
#pragma unroll
        for (int j = 0; j < 8; ++j) {
            float v = acc[i][j] + bias[cbase + j];
            v = fmaxf(v, 0.f);
            if (RESID) v += resid[(size_t)rrow * 512 + cbase + j];
            vals[j] = v;
        }
        float4* dst = (float4*)&out[(size_t)rrow * 512 + cbase];
        dst[0] = make_float4(vals[0], vals[1], vals[2], vals[3]);
        dst[1] = make_float4(vals[4], vals[5], vals[6], vals[7]);
    }
}

// ---------------------------------------------------------------------------
// MFMA flash attention with Music-Transformer relative position.
// Computes S^T = K·Q^T (16x16x32 bf16 MFMA) so per-lane softmax state indexes
// q = lane&15. P is moved from C-layout to A-layout in-register via shuffles.
// Grid: (8 q-tiles of 128, 64 head-batches), 256 threads (4 waves x 32 q rows).
// ---------------------------------------------------------------------------
__global__ __launch_bounds__(256) void attn_mfma(
        const float* __restrict__ qe, const float* __restrict__ ke,
        const float* __restrict__ ve, const float* __restrict__ pe_k,
        const float* __restrict__ pe_v, float* __restrict__ ao) {
    __shared__ short Ks[64 * 72];      // K tile  [s][d], bf16, stride 72
    __shared__ short Vt[64 * 72];      // V tile transposed [d][s], bf16
    __shared__ float qpeS[128 * 17];   // per-wave [32 q][17 ri]
    __shared__ float wsumS[128 * 17];  // per-wave bucket sums
    __shared__ float alphaS[128];
    __shared__ float lfinS[128];
    __shared__ float pevS[17 * 64];

    const int tid = threadIdx.x;
    const int qt = 7 - (int)blockIdx.x;       // heavy tiles first
    const int hb = blockIdx.y;
    const int h = hb >> 3, b = hb & 7;
    const int t0 = qt * 128;
    const int w = tid >> 6;
    const int lane = tid & 63;
    const int g = lane >> 4;
    const int n15 = lane & 15;
    const int qbase = t0 + w * 32;

    float* qpeW  = qpeS  + w * (32 * 17);
    float* wsumW = wsumS + w * (32 * 17);
    float* alphaW = alphaS + w * 32;
    float* lW = lfinS + w * 32;

    for (int i = tid; i < 17 * 64; i += 256) pevS[i] = pe_v[i];

    // Persistent Q B-fragments: B[k=d][n=q], lane holds q=n15, d=kh*32+g*8+j
    bf16x8 Bq[2][2];
#pragma unroll
    for (int nt = 0; nt < 2; ++nt)
#pragma unroll
    for (int kh = 0; kh < 2; ++kh) {
        const float* src = qe + (size_t)(b * T_SEQ + qbase + nt * 16 + n15) * U_DIM
                           + h * 64 + kh * 32 + g * 8;
        float4 f0 = *(const float4*)src;
        float4 f1 = *(const float4*)(src + 4);
        bf16x8 fr;
        fr[0] = (short)f2bf(f0.x); fr[1] = (short)f2bf(f0.y);
        fr[2] = (short)f2bf(f0.z); fr[3] = (short)f2bf(f0.w);
        fr[4] = (short)f2bf(f1.x); fr[5] = (short)f2bf(f1.y);
        fr[6] = (short)f2bf(f1.z); fr[7] = (short)f2bf(f1.w);
        Bq[nt][kh] = fr;
    }

    // qpe[q][ri] = Q[q]·pe_k[ri] via MFMA: D[ri][q] = pe_k · Q^T
    {
        f32x4 qa[2][2];
#pragma unroll
        for (int mt = 0; mt < 2; ++mt)
#pragma unroll
        for (int nt = 0; nt < 2; ++nt) qa[mt][nt] = (f32x4){0.f, 0.f, 0.f, 0.f};
#pragma unroll
        for (int mt = 0; mt < 2; ++mt)
#pragma unroll
        for (int kh = 0; kh < 2; ++kh) {
            const float* src = pe_k + (mt * 16 + n15) * 64 + kh * 32 + g * 8;
            float4 f0 = *(const float4*)src;
            float4 f1 = *(const float4*)(src + 4);
            bf16x8 fr;
            fr[0] = (short)f2bf(f0.x); fr[1] = (short)f2bf(f0.y);
            fr[2] = (short)f2bf(f0.z); fr[3] = (short)f2bf(f0.w);
            fr[4] = (short)f2bf(f1.x); fr[5] = (short)f2bf(f1.y);
            fr[6] = (short)f2bf(f1.z); fr[7] = (short)f2bf(f1.w);
#pragma unroll
            for (int nt = 0; nt < 2; ++nt)
                qa[mt][nt] = __builtin_amdgcn_mfma_f32_16x16x32_bf16(fr, Bq[nt][kh], qa[mt][nt], 0, 0, 0);
        }
#pragma unroll
        for (int mt = 0; mt < 2; ++mt)
#pragma unroll
        for (int nt = 0; nt < 2; ++nt)
#pragma unroll
        for (int r = 0; r < 4; ++r) {
            const int ri = mt * 16 + 4 * g + r;
            if (ri <= 16) qpeW[(nt * 16 + n15) * 17 + ri] = qa[mt][nt][r];
        }
    }

    for (int i = lane; i < 32 * 17; i += 64) wsumW[i] = 0.f;

    float m_r[2] = {-3.0e38f, -3.0e38f};
    float l_r[2] = {0.f, 0.f};
    float b0[2]  = {0.f, 0.f};
    f32x4 oacc[2][4];
#pragma unroll
    for (int nt = 0; nt < 2; ++nt)
#pragma unroll
    for (int dt = 0; dt < 4; ++dt) oacc[nt][dt] = (f32x4){0.f, 0.f, 0.f, 0.f};

    const int wqhi = qbase + 31;
    const int send = t0 + 127;

    for (int s0 = 0; s0 <= send; s0 += 64) {
        __syncthreads();
        // stage K [s][d]
        {
            const int sl = tid >> 2, dseg = (tid & 3) * 16;
            const float* src = ke + (size_t)(b * T_SEQ + s0 + sl) * U_DIM + h * 64 + dseg;
            float4 a0 = *(const float4*)(src);
            float4 a1 = *(const float4*)(src + 4);
            float4 a2 = *(const float4*)(src + 8);
            float4 a3 = *(const float4*)(src + 12);
            int2* dst = (int2*)(Ks + sl * 72 + dseg);
            dst[0] = make_int2(packbf(a0.x, a0.y), packbf(a0.z, a0.w));
            dst[1] = make_int2(packbf(a1.x, a1.y), packbf(a1.z, a1.w));
            dst[2] = make_int2(packbf(a2.x, a2.y), packbf(a2.z, a2.w));
            dst[3] = make_int2(packbf(a3.x, a3.y), packbf(a3.z, a3.w));
        }
        // stage V transposed [d][s] (s pairs packed as dwords -> 2-way-free writes)
        {
            const int sp = tid & 31, dbase = (tid >> 5) * 8;
            const float* r0 = ve + (size_t)(b * T_SEQ + s0 + 2 * sp) * U_DIM + h * 64 + dbase;
            const float* r1 = r0 + U_DIM;
            float4 x0 = *(const float4*)(r0);
            float4 x1 = *(const float4*)(r0 + 4);
            float4 y0 = *(const float4*)(r1);
            float4 y1 = *(const float4*)(r1 + 4);
            const float xs[8] = {x0.x, x0.y, x0.z, x0.w, x1.x, x1.y, x1.z, x1.w};
            const float ys[8] = {y0.x, y0.y, y0.z, y0.w, y1.x, y1.y, y1.z, y1.w};
#pragma unroll
            for (int i = 0; i < 8; ++i)
                *(int*)(Vt + (dbase + i) * 72 + 2 * sp) = packbf(xs[i], ys[i]);
        }
        __syncthreads();

        if (s0 > wqhi) continue;   // wave done (both barriers above are always hit)

        // tile classes: 0=fully masked, 1=fully below band (ri==0), 2=crossing
        int cls[4][2];
#pragma unroll
        for (int mt = 0; mt < 4; ++mt)
#pragma unroll
        for (int nt = 0; nt < 2; ++nt) {
            const int slo = s0 + mt * 16;
            const int qlo = qbase + nt * 16;
            cls[mt][nt] = (slo > qlo + 15) ? 0 : ((slo + 31 < qlo) ? 1 : 2);
        }

        // S^T = K·Q^T
        f32x4 c[4][2];
#pragma unroll
        for (int mt = 0; mt < 4; ++mt)
#pragma unroll
        for (int nt = 0; nt < 2; ++nt) c[mt][nt] = (f32x4){0.f, 0.f, 0.f, 0.f};
#pragma unroll
        for (int mt = 0; mt < 4; ++mt) {
            if (cls[mt][0] == 0 && cls[mt][1] == 0) continue;
#pragma unroll
            for (int kh = 0; kh < 2; ++kh) {
                bf16x8 ak = *(const bf16x8*)(Ks + (mt * 16 + n15) * 72 + kh * 32 + g * 8);
#pragma unroll
                for (int nt = 0; nt < 2; ++nt)
                    if (cls[mt][nt])
                        c[mt][nt] = __builtin_amdgcn_mfma_f32_16x16x32_bf16(ak, Bq[nt][kh], c[mt][nt], 0, 0, 0);
            }
        }

        // online softmax (per-lane q = n15)
        float p[4][2][4];
        float alpha_l[2];
#pragma unroll
        for (int nt = 0; nt < 2; ++nt) {
            const int qg = qbase + nt * 16 + n15;
            const float qpe0 = qpeW[(nt * 16 + n15) * 17];
            float sc[4][4];
            float pmax = -3.0e38f;
#pragma unroll
            for (int mt = 0; mt < 4; ++mt) {
                if (cls[mt][nt] == 0) {
#pragma unroll
                    for (int r = 0; r < 4; ++r) sc[mt][r] = -3.0e38f;
                } else if (cls[mt][nt] == 1) {
#pragma unroll
                    for (int r = 0; r < 4; ++r) {
                        sc[mt][r] = (c[mt][nt][r] + qpe0) * 0.125f;
                        pmax = fmaxf(pmax, sc[mt][r]);
                    }
                } else {
#pragma unroll
                    for (int r = 0; r < 4; ++r) {
                        const int sg = s0 + mt * 16 + 4 * g + r;
                        const int dlt = sg - qg;
                        if (dlt <= 0) {
                            const int ri = (dlt < -16) ? 0 : (dlt + 16);
                            sc[mt][r] = (c[mt][nt][r] + qpeW[(nt * 16 + n15) * 17 + ri]) * 0.125f;
                            pmax = fmaxf(pmax, sc[mt][r]);
                        } else {
                            sc[mt][r] = -3.0e38f;
                        }
                    }
                }
            }
            pmax = fmaxf(pmax, __shfl_xor(pmax, 16, 64));
            pmax = fmaxf(pmax, __shfl_xor(pmax, 32, 64));
            const float mnew = fmaxf(m_r[nt], pmax);
            const float alpha = __expf(m_r[nt] - mnew);
            float psum = 0.f;
#pragma unroll
            for (int mt = 0; mt < 4; ++mt)
#pragma unroll
            for (int r = 0; r < 4; ++r) {
                const float pv = (cls[mt][nt] == 0) ? 0.f : __expf(sc[mt][r] - mnew);
                p[mt][nt][r] = pv;
                psum += pv;
            }
            psum += __shfl_xor(psum, 16, 64);
            psum += __shfl_xor(psum, 32, 64);
            l_r[nt] = l_r[nt] * alpha + psum;
            m_r[nt] = mnew;
            alpha_l[nt] = alpha;
            b0[nt] *= alpha;
        }

        // publish alpha, rescale LDS buckets, then add this block's mass
        if (g == 0) { alphaW[n15] = alpha_l[0]; alphaW[16 + n15] = alpha_l[1]; }
        for (int i = lane; i < 544; i += 64) wsumW[i] *= alphaW[i / 17];
#pragma unroll
        for (int nt = 0; nt < 2; ++nt) {
            const int qg = qbase + nt * 16 + n15;
#pragma unroll
            for (int mt = 0; mt < 4; ++mt) {
                if (cls[mt][nt] == 1) {
                    b0[nt] += p[mt][nt][0] + p[mt][nt][1] + p[mt][nt][2] + p[mt][nt][3];
                } else if (cls[mt][nt] == 2) {
#pragma unroll
                    for (int r = 0; r < 4; ++r) {
                        const int sg = s0 + mt * 16 + 4 * g + r;
                        const int dlt = sg - qg;
                        if (dlt <= 0) {
                            if (dlt >= -16)
                                atomicAdd(&wsumW[(nt * 16 + n15) * 17 + dlt + 16], p[mt][nt][r]);
                            else
                                b0[nt] += p[mt][nt][r];
                        }
                    }
                }
            }
        }

        // P: C-layout -> A-layout in-register; O = O*alpha + P·V
        int pk01[4][2], pk23[4][2];
#pragma unroll
        for (int mt = 0; mt < 4; ++mt)
#pragma unroll
        for (int nt = 0; nt < 2; ++nt) {
            pk01[mt][nt] = packbf(p[mt][nt][0], p[mt][nt][1]);
            pk23[mt][nt] = packbf(p[mt][nt][2], p[mt][nt][3]);
        }
        const int srcA = ((g & 1) * 2) * 16 + n15;
        const int srcB = srcA + 16;
        const bool selHi = (g >> 1) != 0;
#pragma unroll
        for (int nt = 0; nt < 2; ++nt) {
            float aO[4];
#pragma unroll
            for (int r = 0; r < 4; ++r) aO[r] = alphaW[nt * 16 + 4 * g + r];
#pragma unroll
            for (int dt = 0; dt < 4; ++dt)
#pragma unroll
            for (int r = 0; r < 4; ++r) oacc[nt][dt][r] *= aO[r];
#pragma unroll
            for (int kh = 0; kh < 2; ++kh) {
                if (cls[2 * kh][nt] == 0 && cls[2 * kh + 1][nt] == 0) continue;
                const int a0l = __shfl(pk01[2 * kh][nt], srcA, 64);
                const int a0h = __shfl(pk01[2 * kh + 1][nt], srcA, 64);
                const int a1l = __shfl(pk23[2 * kh][nt], srcA, 64);
                const int a1h = __shfl(pk23[2 * kh + 1][nt], srcA, 64);
                const int a2l = __shfl(pk01[2 * kh][nt], srcB, 64);
                const int a2h = __shfl(pk01[2 * kh + 1][nt], srcB, 64);
                const int a3l = __shfl(pk23[2 * kh][nt], srcB, 64);
                const int a3h = __shfl(pk23[2 * kh + 1][nt], srcB, 64);
                union { int i[4]; bf16x8 v; } au;
                au.i[0] = selHi ? a0h : a0l;
                au.i[1] = selHi ? a1h : a1l;
                au.i[2] = selHi ? a2h : a2l;
                au.i[3] = selHi ? a3h : a3l;
#pragma unroll
                for (int dt = 0; dt < 4; ++dt) {
                    bf16x8 bv = *(const bf16x8*)(Vt + (dt * 16 + n15) * 72 + kh * 32 + g * 8);
                    oacc[nt][dt] = __builtin_amdgcn_mfma_f32_16x16x32_bf16(au.v, bv, oacc[nt][dt], 0, 0, 0);
                }
            }
        }
    }

    // epilogue: flush bucket-0, publish l, add rel-v term, normalize, store
#pragma unroll
    for (int nt = 0; nt < 2; ++nt) {
        float t = b0[nt];
        t += __shfl_xor(t, 16, 64);
        t += __shfl_xor(t, 32, 64);
        if (g == 0) wsumW[(nt * 16 + n15) * 17] += t;
    }
    if (g == 0) { lW[n15] = l_r[0]; lW[16 + n15] = l_r[1]; }

#pragma unroll
    for (int nt = 0; nt < 2; ++nt)
#pragma unroll
    for (int r = 0; r < 4; ++r) {
        const int ql = nt * 16 + 4 * g + r;
        const int qg = qbase + ql;
        const float linv = 1.0f / lW[ql];
        float w17[17];
#pragma unroll
        for (int ri = 0; ri < 17; ++ri) w17[ri] = wsumW[ql * 17 + ri];
        float* dst = ao + (size_t)(b * T_SEQ + qg) * U_DIM + h * 64 + n15;
#pragma unroll
        for (int dt = 0; dt < 4; ++dt) {
            float relv = 0.f;
#pragma unroll
            for (int ri = 0; ri < 17; ++ri) relv += w17[ri] * pevS[ri * 64 + dt * 16 + n15];
            dst[dt * 16] = (oacc[nt][dt][r] + relv) * linv;
        }
    }
}

// ---------------------------------------------------------------------------
// Row LayerNorm (in-place on [8192, 512])
// ---------------------------------------------------------------------------
__global__ __launch_bounds__(256) void ln_kernel(float* __restrict__ io,
                                                 const float* __restrict__ gamma,
                                                 const float* __restrict__ beta) {
    const int row = blockIdx.x;
    const int tid = threadIdx.x;
    float* rp = &io[(size_t)row * 512];
    float2 v = *(float2*)&rp[tid * 2];

    float s = v.x + v.y;
#pragma unroll
    for (int off = 32; off > 0; off >>= 1) s += __shfl_down(s, off);

    __shared__ float red[4];
    __shared__ float bc[2];
    const int wid = tid >> 6, lane = tid & 63;
    if (lane == 0) red[wid] = s;
    __syncthreads();
    if (tid == 0) bc[0] = (red[0] + red[1] + red[2] + red[3]) * (1.0f / 512.0f);
    __syncthreads();
    const float mu = bc[0];

    const float d0 = v.x - mu, d1 = v.y - mu;
    float sq = d0 * d0 + d1 * d1;
#pragma unroll
    for (int off = 32; off > 0; off >>= 1) sq += __shfl_down(sq, off);
    if (lane == 0) red[wid] = sq;
    __syncthreads();
    if (tid == 0)
        bc[1] = rsqrtf((red[0] + red[1] + red[2] + red[3]) * (1.0f / 512.0f) + LN_EPS);
    __syncthreads();
    const float rs = bc[1];

    const int c = tid * 2;
    float2 o;
    o.x = d0 * rs * gamma[c] + beta[c];
    o.y = d1 * rs * gamma[c + 1] + beta[c + 1];
    *(float2*)&rp[c] = o;
}

// ---------------------------------------------------------------------------
extern "C" void kernel_launch(void* const* d_in, const int* in_sizes, int n_in,
                              void* d_out, int out_size, void* d_ws, size_t ws_size,
                              hipStream_t stream) {
    const float* q     = (const float*)d_in[0];
    const float* k     = (const float*)d_in[1];
    const float* v     = (const float*)d_in[2];
    const float* Wq    = (const float*)d_in[3];
    const float* bq    = (const float*)d_in[4];
    const float* Wk    = (const float*)d_in[5];
    const float* bk    = (const float*)d_in[6];
    const float* Wv    = (const float*)d_in[7];
    const float* bv    = (const float*)d_in[8];
    const float* Wo    = (const float*)d_in[9];
    const float* bo    = (const float*)d_in[10];
    const float* gamma = (const float*)d_in[11];
    const float* beta  = (const float*)d_in[12];
    const float* pe_k  = (const float*)d_in[13];
    const float* pe_v  = (const float*)d_in[14];
    float* out = (float*)d_out;

    const size_t SZ = (size_t)8 * T_SEQ * U_DIM;
    float* qe = (float*)d_ws;
    float* ke = qe + SZ;
    float* ve = ke + SZ;
    float* ao = ve + SZ;

    dim3 gg(128, 4), bb(256);
    gemm512<0><<<gg, bb, 0, stream>>>(q, Wq, bq, nullptr, qe);
    gemm512<0><<<gg, bb, 0, stream>>>(k, Wk, bk, nullptr, ke);
    gemm512<0><<<gg, bb, 0, stream>>>(v, Wv, bv, nullptr, ve);
    attn_mfma<<<dim3(8, 64), bb, 0, stream>>>(qe, ke, ve, pe_k, pe_v, ao);
    gemm512<1><<<gg, bb, 0, stream>>>(ao, Wo, bo, q, out);
    ln_kernel<<<dim3(8192), bb, 0, stream>>>(out, gamma, beta);
}

// Round 5
// 282.230 us; speedup vs baseline: 4.3836x; 1.6604x over previous
//
#include <hip/hip_runtime.h>
#include <hip/hip_bf16.h>

// Problem constants
#define T_SEQ 1024
#define U_DIM 512
#define LN_EPS 1e-3f

typedef float  f32x4  __attribute__((ext_vector_type(4)));
typedef short  bf16x8 __attribute__((ext_vector_type(8)));

__device__ __forceinline__ unsigned short f2bf(float f) {
    union { float f; unsigned u; } x; x.f = f;
    unsigned r = x.u + 0x7fffu + ((x.u >> 16) & 1u);   // RNE
    return (unsigned short)(r >> 16);
}
__device__ __forceinline__ int packbf(float a, float b) {
    return (int)((unsigned)f2bf(a) | ((unsigned)f2bf(b) << 16));
}
__device__ __forceinline__ void async_copy16(void* lds, const void* g) {
    __builtin_amdgcn_global_load_lds((const __attribute__((address_space(1))) void*)g,
                                     (__attribute__((address_space(3))) void*)lds, 16, 0, 0);
}

// ---------------------------------------------------------------------------
// prep_wt: W[k][n] fp32 -> Wt[n][k] bf16 (row-major 512x512), 4 matrices.
// ---------------------------------------------------------------------------
__global__ __launch_bounds__(256) void prep_wt(const float* __restrict__ W0,
                                               const float* __restrict__ W1,
                                               const float* __restrict__ W2,
                                               const float* __restrict__ W3,
                                               short* __restrict__ wt) {
    __shared__ float Ws[64][65];
    const int z = blockIdx.z;
    const float* W = (z == 0) ? W0 : (z == 1) ? W1 : (z == 2) ? W2 : W3;
    short* Wt = wt + (size_t)z * 262144;
    const int k0 = blockIdx.x * 64, n0 = blockIdx.y * 64;
    const int t = threadIdx.x;
    {
        const int kr = t >> 2, cs = (t & 3) * 16;
        const float4* src = (const float4*)(W + (size_t)(k0 + kr) * 512 + n0 + cs);
#pragma unroll
        for (int i = 0; i < 4; ++i) {
            float4 v = src[i];
            Ws[kr][cs + 4 * i + 0] = v.x;
            Ws[kr][cs + 4 * i + 1] = v.y;
            Ws[kr][cs + 4 * i + 2] = v.z;
            Ws[kr][cs + 4 * i + 3] = v.w;
        }
    }
    __syncthreads();
    {
        const int nr = t >> 2, ks = (t & 3) * 16;
        int4 w0, w1;
        w0.x = packbf(Ws[ks + 0][nr], Ws[ks + 1][nr]);
        w0.y = packbf(Ws[ks + 2][nr], Ws[ks + 3][nr]);
        w0.z = packbf(Ws[ks + 4][nr], Ws[ks + 5][nr]);
        w0.w = packbf(Ws[ks + 6][nr], Ws[ks + 7][nr]);
        w1.x = packbf(Ws[ks + 8][nr], Ws[ks + 9][nr]);
        w1.y = packbf(Ws[ks + 10][nr], Ws[ks + 11][nr]);
        w1.z = packbf(Ws[ks + 12][nr], Ws[ks + 13][nr]);
        w1.w = packbf(Ws[ks + 14][nr], Ws[ks + 15][nr]);
        short* dst = Wt + (size_t)(n0 + nr) * 512 + k0 + ks;
        *(int4*)dst = w0;
        *(int4*)(dst + 8) = w1;
    }
}

// ---------------------------------------------------------------------------
// MFMA GEMM: out[8192,512] = relu(A[8192,512] @ W + bias) (+resid for OUT=1)
// AFP32=1: A fp32 (VGPR convert staging). AFP32=0: A bf16 (global_load_lds).
// OUT=0: bf16 output. OUT=1: fp32 output + residual add after relu.
// Tiles: BM=128, BN=128, BK=64. 4 waves, each 64x64. LDS in fragment-cell
// layout: cell(kc,t) = 64 lanes x 16B, so ds_read_b128 at lane*16 is linear.
// ---------------------------------------------------------------------------
template <int AFP32, int OUT>
__global__ __launch_bounds__(256) void gemm_mfma(
        const void* __restrict__ A0, const void* __restrict__ A1, const void* __restrict__ A2,
        const short* __restrict__ Wt0, const short* __restrict__ Wt1, const short* __restrict__ Wt2,
        const float* __restrict__ b0p, const float* __restrict__ b1p, const float* __restrict__ b2p,
        const float* __restrict__ resid,
        void* __restrict__ O0, void* __restrict__ O1, void* __restrict__ O2) {
    __shared__ short As[8192];   // 16 cells of 512 shorts: (kc*8+mt)*512 + lane*8
    __shared__ short Bs[8192];   // 16 cells: (kc*8+nt)*512 + lane*8

    const int z = blockIdx.z;
    const void* Av = (z == 0) ? A0 : (z == 1) ? A1 : A2;
    const short* Wz = (z == 0) ? Wt0 : (z == 1) ? Wt1 : Wt2;
    const float* bz = (z == 0) ? b0p : (z == 1) ? b1p : b2p;
    void* Ov = (z == 0) ? O0 : (z == 1) ? O1 : O2;

    const int tid = threadIdx.x;
    const int m0 = blockIdx.x * 128, n0 = blockIdx.y * 128;
    const int w = tid >> 6, lane = tid & 63;
    const int n15 = lane & 15, g = lane >> 4;
    const int mh = w >> 1, nh = w & 1;

    f32x4 acc[4][4];
#pragma unroll
    for (int i = 0; i < 4; ++i)
#pragma unroll
        for (int j = 0; j < 4; ++j) acc[i][j] = (f32x4){0.f, 0.f, 0.f, 0.f};

    const int am = tid >> 1, akh = tid & 1;   // fp32 A staging mapping

    for (int ck = 0; ck < 8; ++ck) {
        const int k0 = ck * 64;
        if (ck) __syncthreads();

        if (AFP32) {
            // all threads: convert-stage A (32 fp32 -> 16 packed ints)
            const float* asrc = (const float*)Av + (size_t)(m0 + am) * 512 + k0 + akh * 32;
            float4 f[8];
#pragma unroll
            for (int i = 0; i < 8; ++i) f[i] = ((const float4*)asrc)[i];
            short* cell = As + (akh * 8 + (am >> 4)) * 512;
#pragma unroll
            for (int gg = 0; gg < 4; ++gg) {
                int4 wv;
                wv.x = packbf(f[2 * gg].x, f[2 * gg].y);
                wv.y = packbf(f[2 * gg].z, f[2 * gg].w);
                wv.z = packbf(f[2 * gg + 1].x, f[2 * gg + 1].y);
                wv.w = packbf(f[2 * gg + 1].z, f[2 * gg + 1].w);
                *(int4*)(cell + ((am & 15) + 16 * gg) * 8) = wv;
            }
            if (w < 2) {   // waves 0,1: async-stage B
#pragma unroll
                for (int i = 0; i < 8; ++i) {
                    const int kc = i >> 2, nt = w * 4 + (i & 3);
                    const short* gp = Wz + (size_t)(n0 + nt * 16 + n15) * 512 + k0 + kc * 32 + g * 8;
                    async_copy16(Bs + (kc * 8 + nt) * 512, gp);
                }
            }
        } else {
            if (w < 2) {   // B
#pragma unroll
                for (int i = 0; i < 8; ++i) {
                    const int kc = i >> 2, nt = w * 4 + (i & 3);
                    const short* gp = Wz + (size_t)(n0 + nt * 16 + n15) * 512 + k0 + kc * 32 + g * 8;
                    async_copy16(Bs + (kc * 8 + nt) * 512, gp);
                }
            } else {       // A (bf16)
#pragma unroll
                for (int i = 0; i < 8; ++i) {
                    const int kc = i >> 2, mt = (w - 2) * 4 + (i & 3);
                    const short* gp = (const short*)Av + (size_t)(m0 + mt * 16 + n15) * 512 + k0 + kc * 32 + g * 8;
                    async_copy16(As + (kc * 8 + mt) * 512, gp);
                }
            }
        }
        __syncthreads();

#pragma unroll
        for (int kc = 0; kc < 2; ++kc) {
            bf16x8 af[4], bf[4];
#pragma unroll
            for (int i = 0; i < 4; ++i)
                af[i] = *(const bf16x8*)(As + (kc * 8 + mh * 4 + i) * 512 + lane * 8);
#pragma unroll
            for (int j = 0; j < 4; ++j)
                bf[j] = *(const bf16x8*)(Bs + (kc * 8 + nh * 4 + j) * 512 + lane * 8);
#pragma unroll
            for (int i = 0; i < 4; ++i)
#pragma unroll
                for (int j = 0; j < 4; ++j)
                    acc[i][j] = __builtin_amdgcn_mfma_f32_16x16x32_bf16(af[i], bf[j], acc[i][j], 0, 0, 0);
        }
    }

    // Epilogue
    const int mbase = m0 + mh * 64 + g * 4;
    const int nbase = n0 + nh * 64 + n15;
    const bool even = (n15 & 1) == 0;
    float bj[4];
#pragma unroll
    for (int j = 0; j < 4; ++j) bj[j] = bz[nbase + j * 16];

#pragma unroll
    for (int i = 0; i < 4; ++i) {
        const int mrow = mbase + i * 16;
#pragma unroll
        for (int j = 0; j < 4; ++j) {
            const int ncol = nbase + j * 16;
            f32x4 a = acc[i][j];
            float v0 = fmaxf(a[0] + bj[j], 0.f);
            float v1 = fmaxf(a[1] + bj[j], 0.f);
            float v2 = fmaxf(a[2] + bj[j], 0.f);
            float v3 = fmaxf(a[3] + bj[j], 0.f);
            if (OUT == 0) {
                unsigned t01 = (unsigned)packbf(v0, v1);
                unsigned t23 = (unsigned)packbf(v2, v3);
                unsigned x01 = (unsigned)__shfl_xor((int)t01, 1, 64);
                unsigned x23 = (unsigned)__shfl_xor((int)t23, 1, 64);
                short* Oz = (short*)Ov;
                if (even) {
                    unsigned d0 = (t01 & 0xffffu) | (x01 << 16);
                    unsigned d1 = (t01 >> 16) | (x01 & 0xffff0000u);
                    *(unsigned*)(Oz + (size_t)(mrow + 0) * 512 + ncol) = d0;
                    *(unsigned*)(Oz + (size_t)(mrow + 1) * 512 + ncol) = d1;
                } else {
                    unsigned d2 = (x23 & 0xffffu) | (t23 << 16);
                    unsigned d3 = (x23 >> 16) | (t23 & 0xffff0000u);
                    *(unsigned*)(Oz + (size_t)(mrow + 2) * 512 + ncol - 1) = d2;
                    *(unsigned*)(Oz + (size_t)(mrow + 3) * 512 + ncol - 1) = d3;
                }
            } else {
                float x0 = __shfl_xor(v0, 1, 64);
                float x1 = __shfl_xor(v1, 1, 64);
                float x2 = __shfl_xor(v2, 1, 64);
                float x3 = __shfl_xor(v3, 1, 64);
                float* Oz = (float*)Ov;
                if (even) {
                    float2 r0 = *(const float2*)(resid + (size_t)(mrow + 0) * 512 + ncol);
                    float2 r1 = *(const float2*)(resid + (size_t)(mrow + 1) * 512 + ncol);
                    *(float2*)(Oz + (size_t)(mrow + 0) * 512 + ncol) = make_float2(v0 + r0.x, x0 + r0.y);
                    *(float2*)(Oz + (size_t)(mrow + 1) * 512 + ncol) = make_float2(v1 + r1.x, x1 + r1.y);
                } else {
                    float2 r2 = *(const float2*)(resid + (size_t)(mrow + 2) * 512 + ncol - 1);
                    float2 r3 = *(const float2*)(resid + (size_t)(mrow + 3) * 512 + ncol - 1);
                    *(float2*)(Oz + (size_t)(mrow + 2) * 512 + ncol - 1) = make_float2(x2 + r2.x, v2 + r2.y);
                    *(float2*)(Oz + (size_t)(mrow + 3) * 512 + ncol - 1) = make_float2(x3 + r3.x, v3 + r3.y);
                }
            }
        }
    }
}

// ---------------------------------------------------------------------------
// MFMA flash attention (bf16 in, bf16 out), relative position k & v tables.
// ---------------------------------------------------------------------------
__global__ __launch_bounds__(256) void attn_mfma(
        const short* __restrict__ qe, const short* __restrict__ ke,
        const short* __restrict__ ve, const float* __restrict__ pe_k,
        const float* __restrict__ pe_v, short* __restrict__ ao) {
    __shared__ short Ks[64 * 72];
    __shared__ short Vt[64 * 72];
    __shared__ float qpeS[128 * 17];
    __shared__ float wsumS[128 * 17];
    __shared__ float alphaS[128];
    __shared__ float lfinS[128];
    __shared__ float pevS[17 * 64];

    const int tid = threadIdx.x;
    const int qt = 7 - (int)blockIdx.x;
    const int hb = blockIdx.y;
    const int h = hb >> 3, b = hb & 7;
    const int t0 = qt * 128;
    const int w = tid >> 6;
    const int lane = tid & 63;
    const int g = lane >> 4;
    const int n15 = lane & 15;
    const int qbase = t0 + w * 32;

    float* qpeW  = qpeS  + w * (32 * 17);
    float* wsumW = wsumS + w * (32 * 17);
    float* alphaW = alphaS + w * 32;
    float* lW = lfinS + w * 32;

    for (int i = tid; i < 17 * 64; i += 256) pevS[i] = pe_v[i];

    // Persistent Q B-fragments (bf16 direct load)
    bf16x8 Bq[2][2];
#pragma unroll
    for (int nt = 0; nt < 2; ++nt)
#pragma unroll
    for (int kh = 0; kh < 2; ++kh)
        Bq[nt][kh] = *(const bf16x8*)(qe + (size_t)(b * T_SEQ + qbase + nt * 16 + n15) * U_DIM
                                      + h * 64 + kh * 32 + g * 8);

    // qpe[q][ri] = Q[q]·pe_k[ri] via MFMA
    {
        f32x4 qa[2][2];
#pragma unroll
        for (int mt = 0; mt < 2; ++mt)
#pragma unroll
        for (int nt = 0; nt < 2; ++nt) qa[mt][nt] = (f32x4){0.f, 0.f, 0.f, 0.f};
#pragma unroll
        for (int mt = 0; mt < 2; ++mt)
#pragma unroll
        for (int kh = 0; kh < 2; ++kh) {
            const float* src = pe_k + (mt * 16 + n15) * 64 + kh * 32 + g * 8;
            float4 f0 = *(const float4*)src;
            float4 f1 = *(const float4*)(src + 4);
            bf16x8 fr;
            fr[0] = (short)f2bf(f0.x); fr[1] = (short)f2bf(f0.y);
            fr[2] = (short)f2bf(f0.z); fr[3] = (short)f2bf(f0.w);
            fr[4] = (short)f2bf(f1.x); fr[5] = (short)f2bf(f1.y);
            fr[6] = (short)f2bf(f1.z); fr[7] = (short)f2bf(f1.w);
#pragma unroll
            for (int nt = 0; nt < 2; ++nt)
                qa[mt][nt] = __builtin_amdgcn_mfma_f32_16x16x32_bf16(fr, Bq[nt][kh], qa[mt][nt], 0, 0, 0);
        }
#pragma unroll
        for (int mt = 0; mt < 2; ++mt)
#pragma unroll
        for (int nt = 0; nt < 2; ++nt)
#pragma unroll
        for (int r = 0; r < 4; ++r) {
            const int ri = mt * 16 + 4 * g + r;
            if (ri <= 16) qpeW[(nt * 16 + n15) * 17 + ri] = qa[mt][nt][r];
        }
    }

    for (int i = lane; i < 32 * 17; i += 64) wsumW[i] = 0.f;

    float m_r[2] = {-3.0e38f, -3.0e38f};
    float l_r[2] = {0.f, 0.f};
    float b0[2]  = {0.f, 0.f};
    f32x4 oacc[2][4];
#pragma unroll
    for (int nt = 0; nt < 2; ++nt)
#pragma unroll
    for (int dt = 0; dt < 4; ++dt) oacc[nt][dt] = (f32x4){0.f, 0.f, 0.f, 0.f};

    const int wqhi = qbase + 31;
    const int send = t0 + 127;

    for (int s0 = 0; s0 <= send; s0 += 64) {
        __syncthreads();
        // stage K [s][d] (bf16 copy, 16 shorts = 32 bytes per thread)
        {
            const int sl = tid >> 2, dseg = (tid & 3) * 16;
            const short* src = ke + (size_t)(b * T_SEQ + s0 + sl) * U_DIM + h * 64 + dseg;
            *(int4*)(Ks + sl * 72 + dseg)     = *(const int4*)src;
            *(int4*)(Ks + sl * 72 + dseg + 8) = *(const int4*)(src + 8);
        }
        // stage V transposed [d][s]
        {
            const int sp = tid & 31, dbase = (tid >> 5) * 8;
            const short* r0 = ve + (size_t)(b * T_SEQ + s0 + 2 * sp) * U_DIM + h * 64 + dbase;
            const short* r1 = r0 + U_DIM;
            bf16x8 x8 = *(const bf16x8*)r0;
            bf16x8 y8 = *(const bf16x8*)r1;
#pragma unroll
            for (int i = 0; i < 8; ++i) {
                int pv = (int)((unsigned short)x8[i]) | (((int)(unsigned short)y8[i]) << 16);
                *(int*)(Vt + (dbase + i) * 72 + 2 * sp) = pv;
            }
        }
        __syncthreads();

        if (s0 > wqhi) continue;

        int cls[4][2];
#pragma unroll
        for (int mt = 0; mt < 4; ++mt)
#pragma unroll
        for (int nt = 0; nt < 2; ++nt) {
            const int slo = s0 + mt * 16;
            const int qlo = qbase + nt * 16;
            cls[mt][nt] = (slo > qlo + 15) ? 0 : ((slo + 31 < qlo) ? 1 : 2);
        }

        f32x4 c[4][2];
#pragma unroll
        for (int mt = 0; mt < 4; ++mt)
#pragma unroll
        for (int nt = 0; nt < 2; ++nt) c[mt][nt] = (f32x4){0.f, 0.f, 0.f, 0.f};
#pragma unroll
        for (int mt = 0; mt < 4; ++mt) {
            if (cls[mt][0] == 0 && cls[mt][1] == 0) continue;
#pragma unroll
            for (int kh = 0; kh < 2; ++kh) {
                bf16x8 ak = *(const bf16x8*)(Ks + (mt * 16 + n15) * 72 + kh * 32 + g * 8);
#pragma unroll
                for (int nt = 0; nt < 2; ++nt)
                    if (cls[mt][nt])
                        c[mt][nt] = __builtin_amdgcn_mfma_f32_16x16x32_bf16(ak, Bq[nt][kh], c[mt][nt], 0, 0, 0);
            }
        }

        float p[4][2][4];
        float alpha_l[2];
#pragma unroll
        for (int nt = 0; nt < 2; ++nt) {
            const int qg = qbase + nt * 16 + n15;
            const float qpe0 = qpeW[(nt * 16 + n15) * 17];
            float sc[4][4];
            float pmax = -3.0e38f;
#pragma unroll
            for (int mt = 0; mt < 4; ++mt) {
                if (cls[mt][nt] == 0) {
#pragma unroll
                    for (int r = 0; r < 4; ++r) sc[mt][r] = -3.0e38f;
                } else if (cls[mt][nt] == 1) {
#pragma unroll
                    for (int r = 0; r < 4; ++r) {
                        sc[mt][r] = (c[mt][nt][r] + qpe0) * 0.125f;
                        pmax = fmaxf(pmax, sc[mt][r]);
                    }
                } else {
#pragma unroll
                    for (int r = 0; r < 4; ++r) {
                        const int sg = s0 + mt * 16 + 4 * g + r;
                        const int dlt = sg - qg;
                        if (dlt <= 0) {
                            const int ri = (dlt < -16) ? 0 : (dlt + 16);
                            sc[mt][r] = (c[mt][nt][r] + qpeW[(nt * 16 + n15) * 17 + ri]) * 0.125f;
                            pmax = fmaxf(pmax, sc[mt][r]);
                        } else {
                            sc[mt][r] = -3.0e38f;
                        }
                    }
                }
            }
            pmax = fmaxf(pmax, __shfl_xor(pmax, 16, 64));
            pmax = fmaxf(pmax, __shfl_xor(pmax, 32, 64));
            const float mnew = fmaxf(m_r[nt], pmax);
            const float alpha = __expf(m_r[nt] - mnew);
            float psum = 0.f;
#pragma unroll
            for (int mt = 0; mt < 4; ++mt)
#pragma unroll
            for (int r = 0; r < 4; ++r) {
                const float pv = (cls[mt][nt] == 0) ? 0.f : __expf(sc[mt][r] - mnew);
                p[mt][nt][r] = pv;
                psum += pv;
            }
            psum += __shfl_xor(psum, 16, 64);
            psum += __shfl_xor(psum, 32, 64);
            l_r[nt] = l_r[nt] * alpha + psum;
            m_r[nt] = mnew;
            alpha_l[nt] = alpha;
            b0[nt] *= alpha;
        }

        if (g == 0) { alphaW[n15] = alpha_l[0]; alphaW[16 + n15] = alpha_l[1]; }
        for (int i = lane; i < 544; i += 64) wsumW[i] *= alphaW[i / 17];
#pragma unroll
        for (int nt = 0; nt < 2; ++nt) {
            const int qg = qbase + nt * 16 + n15;
#pragma unroll
            for (int mt = 0; mt < 4; ++mt) {
                if (cls[mt][nt] == 1) {
                    b0[nt] += p[mt][nt][0] + p[mt][nt][1] + p[mt][nt][2] + p[mt][nt][3];
                } else if (cls[mt][nt] == 2) {
#pragma unroll
                    for (int r = 0; r < 4; ++r) {
                        const int sg = s0 + mt * 16 + 4 * g + r;
                        const int dlt = sg - qg;
                        if (dlt <= 0) {
                            if (dlt >= -16)
                                atomicAdd(&wsumW[(nt * 16 + n15) * 17 + dlt + 16], p[mt][nt][r]);
                            else
                                b0[nt] += p[mt][nt][r];
                        }
                    }
                }
            }
        }

        int pk01[4][2], pk23[4][2];
#pragma unroll
        for (int mt = 0; mt < 4; ++mt)
#pragma unroll
        for (int nt = 0; nt < 2; ++nt) {
            pk01[mt][nt] = packbf(p[mt][nt][0], p[mt][nt][1]);
            pk23[mt][nt] = packbf(p[mt][nt][2], p[mt][nt][3]);
        }
        const int srcA = ((g & 1) * 2) * 16 + n15;
        const int srcB = srcA + 16;
        const bool selHi = (g >> 1) != 0;
#pragma unroll
        for (int nt = 0; nt < 2; ++nt) {
            float aO[4];
#pragma unroll
            for (int r = 0; r < 4; ++r) aO[r] = alphaW[nt * 16 + 4 * g + r];
#pragma unroll
            for (int dt = 0; dt < 4; ++dt)
#pragma unroll
            for (int r = 0; r < 4; ++r) oacc[nt][dt][r] *= aO[r];
#pragma unroll
            for (int kh = 0; kh < 2; ++kh) {
                if (cls[2 * kh][nt] == 0 && cls[2 * kh + 1][nt] == 0) continue;
                const int a0l = __shfl(pk01[2 * kh][nt], srcA, 64);
                const int a0h = __shfl(pk01[2 * kh + 1][nt], srcA, 64);
                const int a1l = __shfl(pk23[2 * kh][nt], srcA, 64);
                const int a1h = __shfl(pk23[2 * kh + 1][nt], srcA, 64);
                const int a2l = __shfl(pk01[2 * kh][nt], srcB, 64);
                const int a2h = __shfl(pk01[2 * kh + 1][nt], srcB, 64);
                const int a3l = __shfl(pk23[2 * kh][nt], srcB, 64);
                const int a3h = __shfl(pk23[2 * kh + 1][nt], srcB, 64);
                union { int i[4]; bf16x8 v; } au;
                au.i[0] = selHi ? a0h : a0l;
                au.i[1] = selHi ? a1h : a1l;
                au.i[2] = selHi ? a2h : a2l;
                au.i[3] = selHi ? a3h : a3l;
#pragma unroll
                for (int dt = 0; dt < 4; ++dt) {
                    bf16x8 bv = *(const bf16x8*)(Vt + (dt * 16 + n15) * 72 + kh * 32 + g * 8);
                    oacc[nt][dt] = __builtin_amdgcn_mfma_f32_16x16x32_bf16(au.v, bv, oacc[nt][dt], 0, 0, 0);
                }
            }
        }
    }

#pragma unroll
    for (int nt = 0; nt < 2; ++nt) {
        float t = b0[nt];
        t += __shfl_xor(t, 16, 64);
        t += __shfl_xor(t, 32, 64);
        if (g == 0) wsumW[(nt * 16 + n15) * 17] += t;
    }
    if (g == 0) { lW[n15] = l_r[0]; lW[16 + n15] = l_r[1]; }

#pragma unroll
    for (int nt = 0; nt < 2; ++nt)
#pragma unroll
    for (int r = 0; r < 4; ++r) {
        const int ql = nt * 16 + 4 * g + r;
        const int qg = qbase + ql;
        const float linv = 1.0f / lW[ql];
        float w17[17];
#pragma unroll
        for (int ri = 0; ri < 17; ++ri) w17[ri] = wsumW[ql * 17 + ri];
        short* dst = ao + (size_t)(b * T_SEQ + qg) * U_DIM + h * 64 + n15;
#pragma unroll
        for (int dt = 0; dt < 4; ++dt) {
            float relv = 0.f;
#pragma unroll
            for (int ri = 0; ri < 17; ++ri) relv += w17[ri] * pevS[ri * 64 + dt * 16 + n15];
            dst[dt * 16] = (short)f2bf((oacc[nt][dt][r] + relv) * linv);
        }
    }
}

// ---------------------------------------------------------------------------
// Row LayerNorm (in-place on [8192, 512])
// ---------------------------------------------------------------------------
__global__ __launch_bounds__(256) void ln_kernel(float* __restrict__ io,
                                                 const float* __restrict__ gamma,
                                                 const float* __restrict__ beta) {
    const int row = blockIdx.x;
    const int tid = threadIdx.x;
    float* rp = &io[(size_t)row * 512];
    float2 v = *(float2*)&rp[tid * 2];

    float s = v.x + v.y;
#pragma unroll
    for (int off = 32; off > 0; off >>= 1) s += __shfl_down(s, off);

    __shared__ float red[4];
    __shared__ float bc[2];
    const int wid = tid >> 6, lane = tid & 63;
    if (lane == 0) red[wid] = s;
    __syncthreads();
    if (tid == 0) bc[0] = (red[0] + red[1] + red[2] + red[3]) * (1.0f / 512.0f);
    __syncthreads();
    const float mu = bc[0];

    const float d0 = v.x - mu, d1 = v.y - mu;
    float sq = d0 * d0 + d1 * d1;
#pragma unroll
    for (int off = 32; off > 0; off >>= 1) sq += __shfl_down(sq, off);
    if (lane == 0) red[wid] = sq;
    __syncthreads();
    if (tid == 0)
        bc[1] = rsqrtf((red[0] + red[1] + red[2] + red[3]) * (1.0f / 512.0f) + LN_EPS);
    __syncthreads();
    const float rs = bc[1];

    const int c = tid * 2;
    float2 o;
    o.x = d0 * rs * gamma[c] + beta[c];
    o.y = d1 * rs * gamma[c + 1] + beta[c + 1];
    *(float2*)&rp[c] = o;
}

// ---------------------------------------------------------------------------
extern "C" void kernel_launch(void* const* d_in, const int* in_sizes, int n_in,
                              void* d_out, int out_size, void* d_ws, size_t ws_size,
                              hipStream_t stream) {
    const float* q     = (const float*)d_in[0];
    const float* k     = (const float*)d_in[1];
    const float* v     = (const float*)d_in[2];
    const float* Wq    = (const float*)d_in[3];
    const float* bq    = (const float*)d_in[4];
    const float* Wk    = (const float*)d_in[5];
    const float* bk    = (const float*)d_in[6];
    const float* Wv    = (const float*)d_in[7];
    const float* bv    = (const float*)d_in[8];
    const float* Wo    = (const float*)d_in[9];
    const float* bo    = (const float*)d_in[10];
    const float* gamma = (const float*)d_in[11];
    const float* beta  = (const float*)d_in[12];
    const float* pe_k  = (const float*)d_in[13];
    const float* pe_v  = (const float*)d_in[14];
    float* out = (float*)d_out;

    char* base = (char*)d_ws;
    short* qe = (short*)(base);                          // 8 MB each (bf16 8192x512)
    short* ke = (short*)(base + (((size_t)8) << 20));
    short* ve = (short*)(base + (((size_t)16) << 20));
    short* ao = (short*)(base + (((size_t)24) << 20));
    short* wt = (short*)(base + (((size_t)32) << 20));   // 4 x 512KB bf16 Wt
    short* wtq = wt, *wtk = wt + 262144, *wtv = wt + 2 * 262144, *wto = wt + 3 * 262144;

    prep_wt<<<dim3(8, 8, 4), 256, 0, stream>>>(Wq, Wk, Wv, Wo, wt);
    gemm_mfma<1, 0><<<dim3(64, 4, 3), 256, 0, stream>>>(
        q, k, v, wtq, wtk, wtv, bq, bk, bv, nullptr, qe, ke, ve);
    attn_mfma<<<dim3(8, 64), 256, 0, stream>>>(qe, ke, ve, pe_k, pe_v, ao);
    gemm_mfma<0, 1><<<dim3(64, 4, 1), 256, 0, stream>>>(
        ao, ao, ao, wto, wto, wto, bo, bo, bo, q, out, out, out);
    ln_kernel<<<dim3(8192), 256, 0, stream>>>(out, gamma, beta);
}

// Round 6
// 273.099 us; speedup vs baseline: 4.5302x; 1.0334x over previous
//
#include <hip/hip_runtime.h>
#include <hip/hip_bf16.h>

#define T_SEQ 1024
#define U_DIM 512
#define LN_EPS 1e-3f

typedef float  f32x4  __attribute__((ext_vector_type(4)));
typedef short  bf16x8 __attribute__((ext_vector_type(8)));

__device__ __forceinline__ unsigned short f2bf(float f) {
    union { float f; unsigned u; } x; x.f = f;
    unsigned r = x.u + 0x7fffu + ((x.u >> 16) & 1u);   // RNE
    return (unsigned short)(r >> 16);
}
__device__ __forceinline__ float b2f(short s) {
    union { unsigned u; float f; } x; x.u = ((unsigned)(unsigned short)s) << 16;
    return x.f;
}
__device__ __forceinline__ int packbf(float a, float b) {
    return (int)((unsigned)f2bf(a) | ((unsigned)f2bf(b) << 16));
}
__device__ __forceinline__ void async_copy16(void* lds, const void* g) {
    __builtin_amdgcn_global_load_lds((const __attribute__((address_space(1))) void*)g,
                                     (__attribute__((address_space(3))) void*)lds, 16, 0, 0);
}

// ---------------------------------------------------------------------------
// prep_all: bid<256 -> weight transpose fp32->bf16 Wt[n][k]; else q/k/v fp32->bf16
// ---------------------------------------------------------------------------
__global__ __launch_bounds__(256) void prep_all(
        const float* __restrict__ Wq, const float* __restrict__ Wk,
        const float* __restrict__ Wv, const float* __restrict__ Wo,
        short* __restrict__ wt,
        const float* __restrict__ q, const float* __restrict__ k,
        const float* __restrict__ v,
        short* __restrict__ qb, short* __restrict__ kb, short* __restrict__ vb) {
    __shared__ float Ws[64][65];
    const int bid = blockIdx.x, t = threadIdx.x;
    if (bid < 256) {
        const int z = bid >> 6, tile = bid & 63;
        const float* W = (z == 0) ? Wq : (z == 1) ? Wk : (z == 2) ? Wv : Wo;
        short* Wt = wt + (size_t)z * 262144;
        const int k0 = (tile >> 3) * 64, n0 = (tile & 7) * 64;
        {
            const int kr = t >> 2, cs = (t & 3) * 16;
            const float4* src = (const float4*)(W + (size_t)(k0 + kr) * 512 + n0 + cs);
#pragma unroll
            for (int i = 0; i < 4; ++i) {
                float4 vv = src[i];
                Ws[kr][cs + 4 * i + 0] = vv.x;
                Ws[kr][cs + 4 * i + 1] = vv.y;
                Ws[kr][cs + 4 * i + 2] = vv.z;
                Ws[kr][cs + 4 * i + 3] = vv.w;
            }
        }
        __syncthreads();
        {
            const int nr = t >> 2, ks = (t & 3) * 16;
            int4 w0, w1;
            w0.x = packbf(Ws[ks + 0][nr], Ws[ks + 1][nr]);
            w0.y = packbf(Ws[ks + 2][nr], Ws[ks + 3][nr]);
            w0.z = packbf(Ws[ks + 4][nr], Ws[ks + 5][nr]);
            w0.w = packbf(Ws[ks + 6][nr], Ws[ks + 7][nr]);
            w1.x = packbf(Ws[ks + 8][nr], Ws[ks + 9][nr]);
            w1.y = packbf(Ws[ks + 10][nr], Ws[ks + 11][nr]);
            w1.z = packbf(Ws[ks + 12][nr], Ws[ks + 13][nr]);
            w1.w = packbf(Ws[ks + 14][nr], Ws[ks + 15][nr]);
            short* dst = Wt + (size_t)(n0 + nr) * 512 + k0 + ks;
            *(int4*)dst = w0;
            *(int4*)(dst + 8) = w1;
        }
    } else {
        const int aid = bid - 256;
        const int tsr = aid >> 10, chunk = aid & 1023;
        const float* src = ((tsr == 0) ? q : (tsr == 1) ? k : v) + (size_t)chunk * 4096 + t * 16;
        short* dst = ((tsr == 0) ? qb : (tsr == 1) ? kb : vb) + (size_t)chunk * 4096 + t * 16;
        float4 f0 = ((const float4*)src)[0];
        float4 f1 = ((const float4*)src)[1];
        float4 f2 = ((const float4*)src)[2];
        float4 f3 = ((const float4*)src)[3];
        int4 o0, o1;
        o0.x = packbf(f0.x, f0.y); o0.y = packbf(f0.z, f0.w);
        o0.z = packbf(f1.x, f1.y); o0.w = packbf(f1.z, f1.w);
        o1.x = packbf(f2.x, f2.y); o1.y = packbf(f2.z, f2.w);
        o1.z = packbf(f3.x, f3.y); o1.w = packbf(f3.z, f3.w);
        *(int4*)dst = o0;
        *(int4*)(dst + 8) = o1;
    }
}

// ---------------------------------------------------------------------------
// MFMA GEMM, bf16 A (async staged), bf16 Wt, LDS double-buffered (1 barrier/it)
// OUT=0: bf16 out. OUT=1: fp32 out + residual after relu.
// ---------------------------------------------------------------------------
template <int OUT>
__global__ __launch_bounds__(256) void gemm_bf16(
        const short* __restrict__ A0, const short* __restrict__ A1, const short* __restrict__ A2,
        const short* __restrict__ Wt0, const short* __restrict__ Wt1, const short* __restrict__ Wt2,
        const float* __restrict__ b0p, const float* __restrict__ b1p, const float* __restrict__ b2p,
        const float* __restrict__ resid,
        void* __restrict__ O0, void* __restrict__ O1, void* __restrict__ O2) {
    __shared__ short As[2 * 8192];
    __shared__ short Bs[2 * 8192];

    const int z = blockIdx.z;
    const short* Az = (z == 0) ? A0 : (z == 1) ? A1 : A2;
    const short* Wz = (z == 0) ? Wt0 : (z == 1) ? Wt1 : Wt2;
    const float* bz = (z == 0) ? b0p : (z == 1) ? b1p : b2p;
    void* Ov = (z == 0) ? O0 : (z == 1) ? O1 : O2;

    const int tid = threadIdx.x;
    const int m0 = blockIdx.x * 128, n0 = blockIdx.y * 128;
    const int w = tid >> 6, lane = tid & 63;
    const int n15 = lane & 15, g = lane >> 4;
    const int mh = w >> 1, nh = w & 1;

    f32x4 acc[4][4];
#pragma unroll
    for (int i = 0; i < 4; ++i)
#pragma unroll
        for (int j = 0; j < 4; ++j) acc[i][j] = (f32x4){0.f, 0.f, 0.f, 0.f};

    // stage ck into buf
#define GEMM_STAGE(CK, BUF)                                                              \
    do {                                                                                 \
        const int k0s = (CK) * 64;                                                       \
        short* Ab = As + (BUF) * 8192;                                                   \
        short* Bb = Bs + (BUF) * 8192;                                                   \
        if (w < 2) {                                                                     \
            _Pragma("unroll")                                                            \
            for (int i = 0; i < 8; ++i) {                                                \
                const int kc = i >> 2, nt = w * 4 + (i & 3);                             \
                const short* gp = Wz + (size_t)(n0 + nt * 16 + n15) * 512 + k0s + kc * 32 + g * 8; \
                async_copy16(Bb + (kc * 8 + nt) * 512, gp);                              \
            }                                                                            \
        } else {                                                                         \
            _Pragma("unroll")                                                            \
            for (int i = 0; i < 8; ++i) {                                                \
                const int kc = i >> 2, mt = (w - 2) * 4 + (i & 3);                       \
                const short* gp = Az + (size_t)(m0 + mt * 16 + n15) * 512 + k0s + kc * 32 + g * 8; \
                async_copy16(Ab + (kc * 8 + mt) * 512, gp);                              \
            }                                                                            \
        }                                                                                \
    } while (0)

    GEMM_STAGE(0, 0);
    for (int ck = 0; ck < 8; ++ck) {
        __syncthreads();
        if (ck < 7) GEMM_STAGE(ck + 1, (ck + 1) & 1);
        const int buf = ck & 1;
#pragma unroll
        for (int kc = 0; kc < 2; ++kc) {
            bf16x8 af[4], bfv[4];
#pragma unroll
            for (int i = 0; i < 4; ++i)
                af[i] = *(const bf16x8*)(As + buf * 8192 + (kc * 8 + mh * 4 + i) * 512 + lane * 8);
#pragma unroll
            for (int j = 0; j < 4; ++j)
                bfv[j] = *(const bf16x8*)(Bs + buf * 8192 + (kc * 8 + nh * 4 + j) * 512 + lane * 8);
#pragma unroll
            for (int i = 0; i < 4; ++i)
#pragma unroll
                for (int j = 0; j < 4; ++j)
                    acc[i][j] = __builtin_amdgcn_mfma_f32_16x16x32_bf16(af[i], bfv[j], acc[i][j], 0, 0, 0);
        }
    }
#undef GEMM_STAGE

    // Epilogue
    const int mbase = m0 + mh * 64 + g * 4;
    const int nbase = n0 + nh * 64 + n15;
    const bool even = (n15 & 1) == 0;
    float bj[4];
#pragma unroll
    for (int j = 0; j < 4; ++j) bj[j] = bz[nbase + j * 16];

#pragma unroll
    for (int i = 0; i < 4; ++i) {
        const int mrow = mbase + i * 16;
#pragma unroll
        for (int j = 0; j < 4; ++j) {
            const int ncol = nbase + j * 16;
            f32x4 a = acc[i][j];
            float v0 = fmaxf(a[0] + bj[j], 0.f);
            float v1 = fmaxf(a[1] + bj[j], 0.f);
            float v2 = fmaxf(a[2] + bj[j], 0.f);
            float v3 = fmaxf(a[3] + bj[j], 0.f);
            if (OUT == 0) {
                unsigned t01 = (unsigned)packbf(v0, v1);
                unsigned t23 = (unsigned)packbf(v2, v3);
                unsigned x01 = (unsigned)__shfl_xor((int)t01, 1, 64);
                unsigned x23 = (unsigned)__shfl_xor((int)t23, 1, 64);
                short* Oz = (short*)Ov;
                if (even) {
                    unsigned d0 = (t01 & 0xffffu) | (x01 << 16);
                    unsigned d1 = (t01 >> 16) | (x01 & 0xffff0000u);
                    *(unsigned*)(Oz + (size_t)(mrow + 0) * 512 + ncol) = d0;
                    *(unsigned*)(Oz + (size_t)(mrow + 1) * 512 + ncol) = d1;
                } else {
                    unsigned d2 = (x23 & 0xffffu) | (t23 << 16);
                    unsigned d3 = (x23 >> 16) | (t23 & 0xffff0000u);
                    *(unsigned*)(Oz + (size_t)(mrow + 2) * 512 + ncol - 1) = d2;
                    *(unsigned*)(Oz + (size_t)(mrow + 3) * 512 + ncol - 1) = d3;
                }
            } else {
                float x0 = __shfl_xor(v0, 1, 64);
                float x1 = __shfl_xor(v1, 1, 64);
                float x2 = __shfl_xor(v2, 1, 64);
                float x3 = __shfl_xor(v3, 1, 64);
                float* Oz = (float*)Ov;
                if (even) {
                    float2 r0 = *(const float2*)(resid + (size_t)(mrow + 0) * 512 + ncol);
                    float2 r1 = *(const float2*)(resid + (size_t)(mrow + 1) * 512 + ncol);
                    *(float2*)(Oz + (size_t)(mrow + 0) * 512 + ncol) = make_float2(v0 + r0.x, x0 + r0.y);
                    *(float2*)(Oz + (size_t)(mrow + 1) * 512 + ncol) = make_float2(v1 + r1.x, x1 + r1.y);
                } else {
                    float2 r2 = *(const float2*)(resid + (size_t)(mrow + 2) * 512 + ncol - 1);
                    float2 r3 = *(const float2*)(resid + (size_t)(mrow + 3) * 512 + ncol - 1);
                    *(float2*)(Oz + (size_t)(mrow + 2) * 512 + ncol - 1) = make_float2(x2 + r2.x, v2 + r2.y);
                    *(float2*)(Oz + (size_t)(mrow + 3) * 512 + ncol - 1) = make_float2(x3 + r3.x, v3 + r3.y);
                }
            }
        }
    }
}

// ---------------------------------------------------------------------------
// MFMA flash attention, balanced waves (row-blocks {w, 7-w}), K async staged,
// K/V LDS double-buffer (1 barrier/iter). Writes O/l to ao and (m,l) to ml.
// rel-v handled by band_relv pass.
// ---------------------------------------------------------------------------
__global__ __launch_bounds__(256) void attn_mfma(
        const short* __restrict__ qe, const short* __restrict__ ke,
        const short* __restrict__ ve, const float* __restrict__ pe_k,
        float* __restrict__ ml, short* __restrict__ ao) {
    __shared__ short Kc[2 * 4096];    // dbuf: 8 cells x 512 shorts, cell=(kh*4+mt)
    __shared__ short Vt[2 * 4608];    // dbuf: [d][s] transposed, stride 72
    __shared__ float qpeS[4 * 32 * 17];

    const int tid = threadIdx.x;
    const int qt = 7 - (int)blockIdx.x;
    const int hb = blockIdx.y;
    const int h = hb >> 3, b = hb & 7;
    const int t0 = qt * 128;
    const int w = tid >> 6, lane = tid & 63;
    const int g = lane >> 4, n15 = lane & 15;
    const int qn[2] = {t0 + w * 16, t0 + (7 - w) * 16};   // balanced pair
    const int wqhi = qn[1] + 15;
    const int nsteps = (t0 + 128) >> 6;
    const int sp = tid & 31, dbase = (tid >> 5) * 8;

    float* qpeW = qpeS + w * (32 * 17);

    // Q B-fragments
    bf16x8 Bq[2][2];
#pragma unroll
    for (int nt = 0; nt < 2; ++nt)
#pragma unroll
    for (int kh = 0; kh < 2; ++kh)
        Bq[nt][kh] = *(const bf16x8*)(qe + (size_t)(b * T_SEQ + qn[nt] + n15) * U_DIM
                                      + h * 64 + kh * 32 + g * 8);

    // qpe[q][ri] = Q[q]·pe_k[ri] via MFMA
    {
        f32x4 qa[2][2];
#pragma unroll
        for (int mt = 0; mt < 2; ++mt)
#pragma unroll
        for (int nt = 0; nt < 2; ++nt) qa[mt][nt] = (f32x4){0.f, 0.f, 0.f, 0.f};
#pragma unroll
        for (int mt = 0; mt < 2; ++mt)
#pragma unroll
        for (int kh = 0; kh < 2; ++kh) {
            const float* src = pe_k + (mt * 16 + n15) * 64 + kh * 32 + g * 8;
            float4 f0 = *(const float4*)src;
            float4 f1 = *(const float4*)(src + 4);
            bf16x8 fr;
            fr[0] = (short)f2bf(f0.x); fr[1] = (short)f2bf(f0.y);
            fr[2] = (short)f2bf(f0.z); fr[3] = (short)f2bf(f0.w);
            fr[4] = (short)f2bf(f1.x); fr[5] = (short)f2bf(f1.y);
            fr[6] = (short)f2bf(f1.z); fr[7] = (short)f2bf(f1.w);
#pragma unroll
            for (int nt = 0; nt < 2; ++nt)
                qa[mt][nt] = __builtin_amdgcn_mfma_f32_16x16x32_bf16(fr, Bq[nt][kh], qa[mt][nt], 0, 0, 0);
        }
#pragma unroll
        for (int mt = 0; mt < 2; ++mt)
#pragma unroll
        for (int nt = 0; nt < 2; ++nt)
#pragma unroll
        for (int r = 0; r < 4; ++r) {
            const int ri = mt * 16 + 4 * g + r;
            if (ri <= 16) qpeW[(nt * 16 + n15) * 17 + ri] = qa[mt][nt][r];
        }
    }
    const float qpe0r[2] = { qpeW[(n15) * 17], qpeW[(16 + n15) * 17] };

    float m_r[2] = {-3.0e38f, -3.0e38f};
    float l_r[2] = {0.f, 0.f};
    f32x4 oacc[2][4];
#pragma unroll
    for (int nt = 0; nt < 2; ++nt)
#pragma unroll
    for (int dt = 0; dt < 4; ++dt) oacc[nt][dt] = (f32x4){0.f, 0.f, 0.f, 0.f};

    // prologue: stage s0=0 into buf 0
    {
#pragma unroll
        for (int j = 0; j < 2; ++j) {
            const int cc = 2 * w + j, kh = cc >> 2, mt = cc & 3;
            const short* gp = ke + (size_t)(b * T_SEQ + mt * 16 + n15) * U_DIM + h * 64 + kh * 32 + g * 8;
            async_copy16(Kc + cc * 512, gp);
        }
        const short* r0 = ve + (size_t)(b * T_SEQ + 2 * sp) * U_DIM + h * 64 + dbase;
        bf16x8 vx = *(const bf16x8*)r0, vy = *(const bf16x8*)(r0 + U_DIM);
#pragma unroll
        for (int ii = 0; ii < 8; ++ii) {
            int pv = (int)((unsigned short)vx[ii]) | (((int)(unsigned short)vy[ii]) << 16);
            *(int*)(Vt + (dbase + ii) * 72 + 2 * sp) = pv;
        }
    }

    for (int i = 0; i < nsteps; ++i) {
        const int s0 = i << 6;
        const int cbuf = i & 1, nbuf = cbuf ^ 1;
        const bool hasnext = (i + 1) < nsteps;
        bf16x8 vx, vy;
        __syncthreads();
        if (hasnext) {
            const int sn = s0 + 64;
#pragma unroll
            for (int j = 0; j < 2; ++j) {
                const int cc = 2 * w + j, kh = cc >> 2, mt = cc & 3;
                const short* gp = ke + (size_t)(b * T_SEQ + sn + mt * 16 + n15) * U_DIM + h * 64 + kh * 32 + g * 8;
                async_copy16(Kc + nbuf * 4096 + cc * 512, gp);
            }
            const short* r0 = ve + (size_t)(b * T_SEQ + sn + 2 * sp) * U_DIM + h * 64 + dbase;
            vx = *(const bf16x8*)r0;
            vy = *(const bf16x8*)(r0 + U_DIM);
        }

        if (s0 <= wqhi) {
            int cls[4][2];
#pragma unroll
            for (int mt = 0; mt < 4; ++mt)
#pragma unroll
            for (int nt = 0; nt < 2; ++nt) {
                const int slo = s0 + mt * 16;
                const int qlo = qn[nt];
                cls[mt][nt] = (slo > qlo + 15) ? 0 : ((slo + 31 < qlo) ? 1 : 2);
            }

            f32x4 c[4][2];
#pragma unroll
            for (int mt = 0; mt < 4; ++mt)
#pragma unroll
            for (int nt = 0; nt < 2; ++nt) c[mt][nt] = (f32x4){0.f, 0.f, 0.f, 0.f};
#pragma unroll
            for (int mt = 0; mt < 4; ++mt) {
                if (cls[mt][0] == 0 && cls[mt][1] == 0) continue;
#pragma unroll
                for (int kh = 0; kh < 2; ++kh) {
                    bf16x8 ak = *(const bf16x8*)(Kc + cbuf * 4096 + (kh * 4 + mt) * 512 + lane * 8);
#pragma unroll
                    for (int nt = 0; nt < 2; ++nt)
                        if (cls[mt][nt])
                            c[mt][nt] = __builtin_amdgcn_mfma_f32_16x16x32_bf16(ak, Bq[nt][kh], c[mt][nt], 0, 0, 0);
                }
            }

            float p[4][2][4];
            float alpha_l[2];
#pragma unroll
            for (int nt = 0; nt < 2; ++nt) {
                const int qg = qn[nt] + n15;
                float sc[4][4];
                float pmax = -3.0e38f;
#pragma unroll
                for (int mt = 0; mt < 4; ++mt) {
                    if (cls[mt][nt] == 0) {
#pragma unroll
                        for (int r = 0; r < 4; ++r) sc[mt][r] = -3.0e38f;
                    } else if (cls[mt][nt] == 1) {
#pragma unroll
                        for (int r = 0; r < 4; ++r) {
                            sc[mt][r] = (c[mt][nt][r] + qpe0r[nt]) * 0.125f;
                            pmax = fmaxf(pmax, sc[mt][r]);
                        }
                    } else {
#pragma unroll
                        for (int r = 0; r < 4; ++r) {
                            const int sg = s0 + mt * 16 + 4 * g + r;
                            const int dlt = sg - qg;
                            if (dlt <= 0) {
                                const int ri = (dlt < -16) ? 0 : (dlt + 16);
                                sc[mt][r] = (c[mt][nt][r] + qpeW[(nt * 16 + n15) * 17 + ri]) * 0.125f;
                                pmax = fmaxf(pmax, sc[mt][r]);
                            } else {
                                sc[mt][r] = -3.0e38f;
                            }
                        }
                    }
                }
                pmax = fmaxf(pmax, __shfl_xor(pmax, 16, 64));
                pmax = fmaxf(pmax, __shfl_xor(pmax, 32, 64));
                const float mnew = fmaxf(m_r[nt], pmax);
                const float alpha = __expf(m_r[nt] - mnew);
                float psum = 0.f;
#pragma unroll
                for (int mt = 0; mt < 4; ++mt)
#pragma unroll
                for (int r = 0; r < 4; ++r) {
                    const float pv = (cls[mt][nt] == 0) ? 0.f : __expf(sc[mt][r] - mnew);
                    p[mt][nt][r] = pv;
                    psum += pv;
                }
                psum += __shfl_xor(psum, 16, 64);
                psum += __shfl_xor(psum, 32, 64);
                l_r[nt] = l_r[nt] * alpha + psum;
                m_r[nt] = mnew;
                alpha_l[nt] = alpha;
            }

            int pk01[4][2], pk23[4][2];
#pragma unroll
            for (int mt = 0; mt < 4; ++mt)
#pragma unroll
            for (int nt = 0; nt < 2; ++nt) {
                pk01[mt][nt] = packbf(p[mt][nt][0], p[mt][nt][1]);
                pk23[mt][nt] = packbf(p[mt][nt][2], p[mt][nt][3]);
            }
            const int srcA = ((g & 1) * 2) * 16 + n15;
            const int srcB = srcA + 16;
            const bool selHi = (g >> 1) != 0;
#pragma unroll
            for (int nt = 0; nt < 2; ++nt) {
                float aO[4];
#pragma unroll
                for (int r = 0; r < 4; ++r) aO[r] = __shfl(alpha_l[nt], 4 * g + r, 64);
#pragma unroll
                for (int dt = 0; dt < 4; ++dt)
#pragma unroll
                for (int r = 0; r < 4; ++r) oacc[nt][dt][r] *= aO[r];
#pragma unroll
                for (int kh = 0; kh < 2; ++kh) {
                    if (cls[2 * kh][nt] == 0 && cls[2 * kh + 1][nt] == 0) continue;
                    const int a0l = __shfl(pk01[2 * kh][nt], srcA, 64);
                    const int a0h = __shfl(pk01[2 * kh + 1][nt], srcA, 64);
                    const int a1l = __shfl(pk23[2 * kh][nt], srcA, 64);
                    const int a1h = __shfl(pk23[2 * kh + 1][nt], srcA, 64);
                    const int a2l = __shfl(pk01[2 * kh][nt], srcB, 64);
                    const int a2h = __shfl(pk01[2 * kh + 1][nt], srcB, 64);
                    const int a3l = __shfl(pk23[2 * kh][nt], srcB, 64);
                    const int a3h = __shfl(pk23[2 * kh + 1][nt], srcB, 64);
                    union { int i[4]; bf16x8 v; } au;
                    au.i[0] = selHi ? a0h : a0l;
                    au.i[1] = selHi ? a1h : a1l;
                    au.i[2] = selHi ? a2h : a2l;
                    au.i[3] = selHi ? a3h : a3l;
#pragma unroll
                    for (int dt = 0; dt < 4; ++dt) {
                        bf16x8 bv = *(const bf16x8*)(Vt + cbuf * 4608 + (dt * 16 + n15) * 72 + kh * 32 + g * 8);
                        oacc[nt][dt] = __builtin_amdgcn_mfma_f32_16x16x32_bf16(au.v, bv, oacc[nt][dt], 0, 0, 0);
                    }
                }
            }
        }

        if (hasnext) {
#pragma unroll
            for (int ii = 0; ii < 8; ++ii) {
                int pv = (int)((unsigned short)vx[ii]) | (((int)(unsigned short)vy[ii]) << 16);
                *(int*)(Vt + nbuf * 4608 + (dbase + ii) * 72 + 2 * sp) = pv;
            }
        }
    }

    // epilogue: store m,l then normalized O
#pragma unroll
    for (int nt = 0; nt < 2; ++nt) {
        if (g == 0) {
            float2 v2 = make_float2(m_r[nt], l_r[nt]);
            *(float2*)(ml + ((size_t)hb * T_SEQ + qn[nt] + n15) * 2) = v2;
        }
    }
#pragma unroll
    for (int nt = 0; nt < 2; ++nt)
#pragma unroll
    for (int r = 0; r < 4; ++r) {
        const float lq = __shfl(l_r[nt], 4 * g + r, 64);
        const float linv = 1.0f / lq;
        const int qg = qn[nt] + 4 * g + r;
        short* dst = ao + (size_t)(b * T_SEQ + qg) * U_DIM + h * 64 + n15;
#pragma unroll
        for (int dt = 0; dt < 4; ++dt)
            dst[dt * 16] = (short)f2bf(oacc[nt][dt][r] * linv);
    }
}

// ---------------------------------------------------------------------------
// band_relv: recompute 17-wide diagonal band softmax weights from (m,l),
// add rel-v term (far mass = 1 - band mass goes to pe_v[0]) into ao (RMW).
// grid (16, 64): 64 rows/block, 4 lanes/row.
// ---------------------------------------------------------------------------
__global__ __launch_bounds__(256) void band_relv(
        const short* __restrict__ qe, const short* __restrict__ ke,
        const float* __restrict__ pe_k, const float* __restrict__ pe_v,
        const float* __restrict__ ml, short* __restrict__ ao) {
    __shared__ float pek[17 * 64];
    __shared__ float pev[17 * 64];
    const int tb = blockIdx.x, hb = blockIdx.y;
    const int h = hb >> 3, b = hb & 7;
    const int tid = threadIdx.x;
    for (int i = tid; i < 17 * 64; i += 256) {
        pek[i] = b2f((short)f2bf(pe_k[i]));   // match main kernel's bf16 rounding
        pev[i] = pe_v[i];
    }
    __syncthreads();

    const int t = tb * 64 + (tid >> 2);
    const int p = (tid & 3) * 16;
    const short* qp = qe + (size_t)(b * T_SEQ + t) * U_DIM + h * 64 + p;
    bf16x8 qa = *(const bf16x8*)qp, qb2 = *(const bf16x8*)(qp + 8);
    float qv[16];
#pragma unroll
    for (int i = 0; i < 8; ++i) { qv[i] = b2f(qa[i]); qv[8 + i] = b2f(qb2[i]); }

    float dots[17];
#pragma unroll
    for (int ri = 0; ri < 17; ++ri) {
        const int s = t - 16 + ri;
        float acc = 0.f;
        if (s >= 0) {
            const short* kp = ke + (size_t)(b * T_SEQ + s) * U_DIM + h * 64 + p;
            bf16x8 ka = *(const bf16x8*)kp, kb2 = *(const bf16x8*)(kp + 8);
#pragma unroll
            for (int d = 0; d < 8; ++d) {
                acc += qv[d] * b2f(ka[d]);
                acc += qv[8 + d] * b2f(kb2[d]);
            }
#pragma unroll
            for (int d = 0; d < 16; ++d) acc += qv[d] * pek[ri * 64 + p + d];
        }
        dots[ri] = acc;
    }
#pragma unroll
    for (int ri = 0; ri < 17; ++ri) {
        dots[ri] += __shfl_xor(dots[ri], 1, 64);
        dots[ri] += __shfl_xor(dots[ri], 2, 64);
    }

    const float2 mlv = *(const float2*)(ml + ((size_t)hb * T_SEQ + t) * 2);
    const float m = mlv.x, linv = 1.0f / mlv.y;
    float wv[17];
    float wsum = 0.f;
#pragma unroll
    for (int ri = 0; ri < 17; ++ri) {
        const int s = t - 16 + ri;
        const float wr = (s >= 0) ? __expf(dots[ri] * 0.125f - m) * linv : 0.f;
        wv[ri] = wr;
        wsum += wr;
    }
    wv[0] += 1.0f - wsum;   // far-bucket mass (all s <= t-17)

    float relv[16];
#pragma unroll
    for (int d = 0; d < 16; ++d) relv[d] = 0.f;
#pragma unroll
    for (int ri = 0; ri < 17; ++ri)
#pragma unroll
        for (int d = 0; d < 16; ++d) relv[d] += wv[ri] * pev[ri * 64 + p + d];

    short* op = ao + (size_t)(b * T_SEQ + t) * U_DIM + h * 64 + p;
    bf16x8 a0 = *(const bf16x8*)op, a1 = *(const bf16x8*)(op + 8);
    int4 o0, o1;
    o0.x = packbf(b2f(a0[0]) + relv[0],  b2f(a0[1]) + relv[1]);
    o0.y = packbf(b2f(a0[2]) + relv[2],  b2f(a0[3]) + relv[3]);
    o0.z = packbf(b2f(a0[4]) + relv[4],  b2f(a0[5]) + relv[5]);
    o0.w = packbf(b2f(a0[6]) + relv[6],  b2f(a0[7]) + relv[7]);
    o1.x = packbf(b2f(a1[0]) + relv[8],  b2f(a1[1]) + relv[9]);
    o1.y = packbf(b2f(a1[2]) + relv[10], b2f(a1[3]) + relv[11]);
    o1.z = packbf(b2f(a1[4]) + relv[12], b2f(a1[5]) + relv[13]);
    o1.w = packbf(b2f(a1[6]) + relv[14], b2f(a1[7]) + relv[15]);
    *(int4*)op = o0;
    *(int4*)(op + 8) = o1;
}

// ---------------------------------------------------------------------------
// LayerNorm: one wave per row, shuffle-only reductions.
// ---------------------------------------------------------------------------
__global__ __launch_bounds__(256) void ln_kernel(float* __restrict__ io,
                                                 const float* __restrict__ gamma,
                                                 const float* __restrict__ beta) {
    const int row = blockIdx.x * 4 + (threadIdx.x >> 6);
    const int lane = threadIdx.x & 63;
    float* rp = io + (size_t)row * 512 + lane * 8;
    float4 a = *(const float4*)rp;
    float4 c = *(const float4*)(rp + 4);
    float v[8] = {a.x, a.y, a.z, a.w, c.x, c.y, c.z, c.w};

    float s = v[0] + v[1] + v[2] + v[3] + v[4] + v[5] + v[6] + v[7];
#pragma unroll
    for (int off = 1; off < 64; off <<= 1) s += __shfl_xor(s, off, 64);
    const float mu = s * (1.0f / 512.0f);

    float sq = 0.f;
#pragma unroll
    for (int i = 0; i < 8; ++i) { v[i] -= mu; sq += v[i] * v[i]; }
#pragma unroll
    for (int off = 1; off < 64; off <<= 1) sq += __shfl_xor(sq, off, 64);
    const float rs = rsqrtf(sq * (1.0f / 512.0f) + LN_EPS);

    const float4 g0 = *(const float4*)(gamma + lane * 8);
    const float4 g1 = *(const float4*)(gamma + lane * 8 + 4);
    const float4 b0 = *(const float4*)(beta + lane * 8);
    const float4 b1 = *(const float4*)(beta + lane * 8 + 4);
    float4 o0, o1;
    o0.x = v[0] * rs * g0.x + b0.x;
    o0.y = v[1] * rs * g0.y + b0.y;
    o0.z = v[2] * rs * g0.z + b0.z;
    o0.w = v[3] * rs * g0.w + b0.w;
    o1.x = v[4] * rs * g1.x + b1.x;
    o1.y = v[5] * rs * g1.y + b1.y;
    o1.z = v[6] * rs * g1.z + b1.z;
    o1.w = v[7] * rs * g1.w + b1.w;
    *(float4*)rp = o0;
    *(float4*)(rp + 4) = o1;
}

// ---------------------------------------------------------------------------
extern "C" void kernel_launch(void* const* d_in, const int* in_sizes, int n_in,
                              void* d_out, int out_size, void* d_ws, size_t ws_size,
                              hipStream_t stream) {
    const float* q     = (const float*)d_in[0];
    const float* k     = (const float*)d_in[1];
    const float* v     = (const float*)d_in[2];
    const float* Wq    = (const float*)d_in[3];
    const float* bq    = (const float*)d_in[4];
    const float* Wk    = (const float*)d_in[5];
    const float* bk    = (const float*)d_in[6];
    const float* Wv    = (const float*)d_in[7];
    const float* bv    = (const float*)d_in[8];
    const float* Wo    = (const float*)d_in[9];
    const float* bo    = (const float*)d_in[10];
    const float* gamma = (const float*)d_in[11];
    const float* beta  = (const float*)d_in[12];
    const float* pe_k  = (const float*)d_in[13];
    const float* pe_v  = (const float*)d_in[14];
    float* out = (float*)d_out;

    char* base = (char*)d_ws;
    short* qb = (short*)(base);                          // bf16 raw inputs, 8 MB each
    short* kb = (short*)(base + (((size_t)8) << 20));
    short* vb = (short*)(base + (((size_t)16) << 20));
    short* qe = (short*)(base + (((size_t)24) << 20));   // bf16 embeddings
    short* ke = (short*)(base + (((size_t)32) << 20));
    short* ve = (short*)(base + (((size_t)40) << 20));
    short* ao = (short*)(base + (((size_t)48) << 20));
    short* wt = (short*)(base + (((size_t)56) << 20));   // 4 x 512 KB bf16 Wt
    float* ml = (float*)(base + (((size_t)58) << 20));   // [64][1024][2] fp32
    short* wtq = wt, *wtk = wt + 262144, *wtv = wt + 2 * 262144, *wto = wt + 3 * 262144;

    prep_all<<<dim3(3328), 256, 0, stream>>>(Wq, Wk, Wv, Wo, wt, q, k, v, qb, kb, vb);
    gemm_bf16<0><<<dim3(64, 4, 3), 256, 0, stream>>>(
        qb, kb, vb, wtq, wtk, wtv, bq, bk, bv, nullptr, qe, ke, ve);
    attn_mfma<<<dim3(8, 64), 256, 0, stream>>>(qe, ke, ve, pe_k, ml, ao);
    band_relv<<<dim3(16, 64), 256, 0, stream>>>(qe, ke, pe_k, pe_v, ml, ao);
    gemm_bf16<1><<<dim3(64, 4, 1), 256, 0, stream>>>(
        ao, ao, ao, wto, wto, wto, bo, bo, bo, q, out, out, out);
    ln_kernel<<<dim3(2048), 256, 0, stream>>>(out, gamma, beta);
}

// Round 7
// 268.059 us; speedup vs baseline: 4.6154x; 1.0188x over previous
//
#include <hip/hip_runtime.h>
#include <hip/hip_bf16.h>

#define T_SEQ 1024
#define U_DIM 512
#define LN_EPS 1e-3f

typedef float  f32x4  __attribute__((ext_vector_type(4)));
typedef short  bf16x8 __attribute__((ext_vector_type(8)));

__device__ __forceinline__ unsigned short f2bf(float f) {
    union { float f; unsigned u; } x; x.f = f;
    unsigned r = x.u + 0x7fffu + ((x.u >> 16) & 1u);   // RNE
    return (unsigned short)(r >> 16);
}
__device__ __forceinline__ float b2f(short s) {
    union { unsigned u; float f; } x; x.u = ((unsigned)(unsigned short)s) << 16;
    return x.f;
}
__device__ __forceinline__ int packbf(float a, float b) {
    return (int)((unsigned)f2bf(a) | ((unsigned)f2bf(b) << 16));
}
__device__ __forceinline__ void async_copy16(void* lds, const void* g) {
    __builtin_amdgcn_global_load_lds((const __attribute__((address_space(1))) void*)g,
                                     (__attribute__((address_space(3))) void*)lds, 16, 0, 0);
}

// ---------------------------------------------------------------------------
// prep_wt: W[k][n] fp32 -> Wt[n][k] bf16, 4 matrices. 256 blocks.
// ---------------------------------------------------------------------------
__global__ __launch_bounds__(256) void prep_wt(
        const float* __restrict__ Wq, const float* __restrict__ Wk,
        const float* __restrict__ Wv, const float* __restrict__ Wo,
        short* __restrict__ wt) {
    __shared__ float Ws[64][65];
    const int bid = blockIdx.x, t = threadIdx.x;
    const int z = bid >> 6, tile = bid & 63;
    const float* W = (z == 0) ? Wq : (z == 1) ? Wk : (z == 2) ? Wv : Wo;
    short* Wt = wt + (size_t)z * 262144;
    const int k0 = (tile >> 3) * 64, n0 = (tile & 7) * 64;
    {
        const int kr = t >> 2, cs = (t & 3) * 16;
        const float4* src = (const float4*)(W + (size_t)(k0 + kr) * 512 + n0 + cs);
#pragma unroll
        for (int i = 0; i < 4; ++i) {
            float4 vv = src[i];
            Ws[kr][cs + 4 * i + 0] = vv.x;
            Ws[kr][cs + 4 * i + 1] = vv.y;
            Ws[kr][cs + 4 * i + 2] = vv.z;
            Ws[kr][cs + 4 * i + 3] = vv.w;
        }
    }
    __syncthreads();
    {
        const int nr = t >> 2, ks = (t & 3) * 16;
        int4 w0, w1;
        w0.x = packbf(Ws[ks + 0][nr], Ws[ks + 1][nr]);
        w0.y = packbf(Ws[ks + 2][nr], Ws[ks + 3][nr]);
        w0.z = packbf(Ws[ks + 4][nr], Ws[ks + 5][nr]);
        w0.w = packbf(Ws[ks + 6][nr], Ws[ks + 7][nr]);
        w1.x = packbf(Ws[ks + 8][nr], Ws[ks + 9][nr]);
        w1.y = packbf(Ws[ks + 10][nr], Ws[ks + 11][nr]);
        w1.z = packbf(Ws[ks + 12][nr], Ws[ks + 13][nr]);
        w1.w = packbf(Ws[ks + 14][nr], Ws[ks + 15][nr]);
        short* dst = Wt + (size_t)(n0 + nr) * 512 + k0 + ks;
        *(int4*)dst = w0;
        *(int4*)(dst + 8) = w1;
    }
}

// ---------------------------------------------------------------------------
// MFMA GEMM, LDS double-buffered (1 barrier/iter).
// AFP32=1: A fp32, convert-staged via VGPRs (all threads) + B async (waves 0-1).
// AFP32=0: A bf16 async (waves 2-3) + B async (waves 0-1).
// OUT=0: bf16 out. OUT=1: fp32 out + residual after relu.
// ---------------------------------------------------------------------------
template <int AFP32, int OUT>
__global__ __launch_bounds__(256) void gemm_mfma(
        const void* __restrict__ A0, const void* __restrict__ A1, const void* __restrict__ A2,
        const short* __restrict__ Wt0, const short* __restrict__ Wt1, const short* __restrict__ Wt2,
        const float* __restrict__ b0p, const float* __restrict__ b1p, const float* __restrict__ b2p,
        const float* __restrict__ resid,
        void* __restrict__ O0, void* __restrict__ O1, void* __restrict__ O2) {
    __shared__ short As[2 * 8192];
    __shared__ short Bs[2 * 8192];

    const int z = blockIdx.z;
    const void* Av = (z == 0) ? A0 : (z == 1) ? A1 : A2;
    const short* Wz = (z == 0) ? Wt0 : (z == 1) ? Wt1 : Wt2;
    const float* bz = (z == 0) ? b0p : (z == 1) ? b1p : b2p;
    void* Ov = (z == 0) ? O0 : (z == 1) ? O1 : O2;

    const int tid = threadIdx.x;
    const int m0 = blockIdx.x * 128, n0 = blockIdx.y * 128;
    const int w = tid >> 6, lane = tid & 63;
    const int n15 = lane & 15, g = lane >> 4;
    const int mh = w >> 1, nh = w & 1;
    const int am = tid >> 1, akh = tid & 1;   // fp32 A staging mapping

    f32x4 acc[4][4];
#pragma unroll
    for (int i = 0; i < 4; ++i)
#pragma unroll
        for (int j = 0; j < 4; ++j) acc[i][j] = (f32x4){0.f, 0.f, 0.f, 0.f};

    float4 areg[8];

#define LOAD_A(CK)                                                                       \
    do {                                                                                 \
        const float* asrc = (const float*)Av + (size_t)(m0 + am) * 512 + (CK) * 64 + akh * 32; \
        _Pragma("unroll")                                                                \
        for (int i = 0; i < 8; ++i) areg[i] = ((const float4*)asrc)[i];                  \
    } while (0)

#define STORE_A(BUF)                                                                     \
    do {                                                                                 \
        short* cell = As + (BUF) * 8192 + (akh * 8 + (am >> 4)) * 512;                   \
        _Pragma("unroll")                                                                \
        for (int gg = 0; gg < 4; ++gg) {                                                 \
            int4 wv;                                                                     \
            wv.x = packbf(areg[2 * gg].x, areg[2 * gg].y);                               \
            wv.y = packbf(areg[2 * gg].z, areg[2 * gg].w);                               \
            wv.z = packbf(areg[2 * gg + 1].x, areg[2 * gg + 1].y);                       \
            wv.w = packbf(areg[2 * gg + 1].z, areg[2 * gg + 1].w);                       \
            *(int4*)(cell + ((am & 15) + 16 * gg) * 8) = wv;                             \
        }                                                                                \
    } while (0)

#define STAGE_B(CK, BUF)                                                                 \
    do {                                                                                 \
        if (w < 2) {                                                                     \
            _Pragma("unroll")                                                            \
            for (int i = 0; i < 8; ++i) {                                                \
                const int kc = i >> 2, nt = w * 4 + (i & 3);                             \
                const short* gp = Wz + (size_t)(n0 + nt * 16 + n15) * 512 + (CK) * 64 + kc * 32 + g * 8; \
                async_copy16(Bs + (BUF) * 8192 + (kc * 8 + nt) * 512, gp);               \
            }                                                                            \
        }                                                                                \
    } while (0)

#define STAGE_A_ASYNC(CK, BUF)                                                           \
    do {                                                                                 \
        if (w >= 2) {                                                                    \
            _Pragma("unroll")                                                            \
            for (int i = 0; i < 8; ++i) {                                                \
                const int kc = i >> 2, mt = (w - 2) * 4 + (i & 3);                       \
                const short* gp = (const short*)Av + (size_t)(m0 + mt * 16 + n15) * 512 + (CK) * 64 + kc * 32 + g * 8; \
                async_copy16(As + (BUF) * 8192 + (kc * 8 + mt) * 512, gp);               \
            }                                                                            \
        }                                                                                \
    } while (0)

    // prologue
    if (AFP32) {
        LOAD_A(0);
        STORE_A(0);
        STAGE_B(0, 0);
        LOAD_A(1);
    } else {
        STAGE_B(0, 0);
        STAGE_A_ASYNC(0, 0);
    }

    for (int ck = 0; ck < 8; ++ck) {
        const int cb = ck & 1, nb = cb ^ 1;
        __syncthreads();
        if (ck < 7) {
            STAGE_B(ck + 1, nb);
            if (!AFP32) STAGE_A_ASYNC(ck + 1, nb);
        }
#pragma unroll
        for (int kc = 0; kc < 2; ++kc) {
            bf16x8 af[4], bfv[4];
#pragma unroll
            for (int i = 0; i < 4; ++i)
                af[i] = *(const bf16x8*)(As + cb * 8192 + (kc * 8 + mh * 4 + i) * 512 + lane * 8);
#pragma unroll
            for (int j = 0; j < 4; ++j)
                bfv[j] = *(const bf16x8*)(Bs + cb * 8192 + (kc * 8 + nh * 4 + j) * 512 + lane * 8);
#pragma unroll
            for (int i = 0; i < 4; ++i)
#pragma unroll
                for (int j = 0; j < 4; ++j)
                    acc[i][j] = __builtin_amdgcn_mfma_f32_16x16x32_bf16(af[i], bfv[j], acc[i][j], 0, 0, 0);
        }
        if (AFP32 && ck < 7) {
            STORE_A(nb);
            if (ck < 6) LOAD_A(ck + 2);
        }
    }
#undef LOAD_A
#undef STORE_A
#undef STAGE_B
#undef STAGE_A_ASYNC

    // Epilogue
    const int mbase = m0 + mh * 64 + g * 4;
    const int nbase = n0 + nh * 64 + n15;
    const bool even = (n15 & 1) == 0;
    float bj[4];
#pragma unroll
    for (int j = 0; j < 4; ++j) bj[j] = bz[nbase + j * 16];

#pragma unroll
    for (int i = 0; i < 4; ++i) {
        const int mrow = mbase + i * 16;
#pragma unroll
        for (int j = 0; j < 4; ++j) {
            const int ncol = nbase + j * 16;
            f32x4 a = acc[i][j];
            float v0 = fmaxf(a[0] + bj[j], 0.f);
            float v1 = fmaxf(a[1] + bj[j], 0.f);
            float v2 = fmaxf(a[2] + bj[j], 0.f);
            float v3 = fmaxf(a[3] + bj[j], 0.f);
            if (OUT == 0) {
                unsigned t01 = (unsigned)packbf(v0, v1);
                unsigned t23 = (unsigned)packbf(v2, v3);
                unsigned x01 = (unsigned)__shfl_xor((int)t01, 1, 64);
                unsigned x23 = (unsigned)__shfl_xor((int)t23, 1, 64);
                short* Oz = (short*)Ov;
                if (even) {
                    unsigned d0 = (t01 & 0xffffu) | (x01 << 16);
                    unsigned d1 = (t01 >> 16) | (x01 & 0xffff0000u);
                    *(unsigned*)(Oz + (size_t)(mrow + 0) * 512 + ncol) = d0;
                    *(unsigned*)(Oz + (size_t)(mrow + 1) * 512 + ncol) = d1;
                } else {
                    unsigned d2 = (x23 & 0xffffu) | (t23 << 16);
                    unsigned d3 = (x23 >> 16) | (t23 & 0xffff0000u);
                    *(unsigned*)(Oz + (size_t)(mrow + 2) * 512 + ncol - 1) = d2;
                    *(unsigned*)(Oz + (size_t)(mrow + 3) * 512 + ncol - 1) = d3;
                }
            } else {
                float x0 = __shfl_xor(v0, 1, 64);
                float x1 = __shfl_xor(v1, 1, 64);
                float x2 = __shfl_xor(v2, 1, 64);
                float x3 = __shfl_xor(v3, 1, 64);
                float* Oz = (float*)Ov;
                if (even) {
                    float2 r0 = *(const float2*)(resid + (size_t)(mrow + 0) * 512 + ncol);
                    float2 r1 = *(const float2*)(resid + (size_t)(mrow + 1) * 512 + ncol);
                    *(float2*)(Oz + (size_t)(mrow + 0) * 512 + ncol) = make_float2(v0 + r0.x, x0 + r0.y);
                    *(float2*)(Oz + (size_t)(mrow + 1) * 512 + ncol) = make_float2(v1 + r1.x, x1 + r1.y);
                } else {
                    float2 r2 = *(const float2*)(resid + (size_t)(mrow + 2) * 512 + ncol - 1);
                    float2 r3 = *(const float2*)(resid + (size_t)(mrow + 3) * 512 + ncol - 1);
                    *(float2*)(Oz + (size_t)(mrow + 2) * 512 + ncol - 1) = make_float2(x2 + r2.x, v2 + r2.y);
                    *(float2*)(Oz + (size_t)(mrow + 3) * 512 + ncol - 1) = make_float2(x3 + r3.x, v3 + r3.y);
                }
            }
        }
    }
}

// ---------------------------------------------------------------------------
// MFMA flash attention, paired 64-row q-tiles {bx, 15-bx}: every block runs a
// uniform 17 s-steps. 4 waves x 16 q rows. K async-staged cell layout; V in
// cell layout (conflict-free b128 reads). Cross-phase prefetch. Writes O/l to
// ao and (m,l) to ml; rel-v handled by band_relv.
// ---------------------------------------------------------------------------
__global__ __launch_bounds__(256) void attn_mfma(
        const short* __restrict__ qe, const short* __restrict__ ke,
        const short* __restrict__ ve, const float* __restrict__ pe_k,
        float* __restrict__ ml, short* __restrict__ ao) {
    __shared__ short Kc[2 * 4096];    // 8 cells x 512 shorts per buf: (kh*4+mt)
    __shared__ short Vc[2 * 4096];    // 8 cells: (kh*4+dt)
    __shared__ float qpeS[4 * 16 * 17];

    const int tid = threadIdx.x;
    const int bx = blockIdx.x;        // pair index: tiles {bx, 15-bx}
    const int hb = blockIdx.y;
    const int h = hb >> 3, b = hb & 7;
    const int w = tid >> 6, lane = tid & 63;
    const int g = lane >> 4, n15 = lane & 15;
    const int sp = tid & 31, dbase = (tid >> 5) * 8;
    const int tA = bx;                // phase-0 tile (steps 0..tA)
    float* qpeW = qpeS + w * (16 * 17);

    const size_t rowbase = (size_t)b * T_SEQ;

    int qn = 0;
    bf16x8 Bq[2];
    float qpe0 = 0.f;
    float m_r = -3.0e38f, l_r = 0.f;
    f32x4 oacc[4];

    // ---- phase setup: load Q frags, qpe table, reset state ----
#define SETUP(TILE)                                                                      \
    do {                                                                                 \
        qn = (TILE) * 64 + w * 16;                                                       \
        _Pragma("unroll")                                                                \
        for (int kh = 0; kh < 2; ++kh)                                                   \
            Bq[kh] = *(const bf16x8*)(qe + (rowbase + qn + n15) * U_DIM + h * 64 + kh * 32 + g * 8); \
        f32x4 qa[2];                                                                     \
        qa[0] = (f32x4){0.f, 0.f, 0.f, 0.f};                                             \
        qa[1] = (f32x4){0.f, 0.f, 0.f, 0.f};                                             \
        _Pragma("unroll")                                                                \
        for (int mt = 0; mt < 2; ++mt)                                                   \
        _Pragma("unroll")                                                                \
        for (int kh = 0; kh < 2; ++kh) {                                                 \
            const float* src = pe_k + (mt * 16 + n15) * 64 + kh * 32 + g * 8;            \
            float4 f0 = *(const float4*)src;                                             \
            float4 f1 = *(const float4*)(src + 4);                                       \
            bf16x8 fr;                                                                   \
            fr[0] = (short)f2bf(f0.x); fr[1] = (short)f2bf(f0.y);                        \
            fr[2] = (short)f2bf(f0.z); fr[3] = (short)f2bf(f0.w);                        \
            fr[4] = (short)f2bf(f1.x); fr[5] = (short)f2bf(f1.y);                        \
            fr[6] = (short)f2bf(f1.z); fr[7] = (short)f2bf(f1.w);                        \
            qa[mt] = __builtin_amdgcn_mfma_f32_16x16x32_bf16(fr, Bq[kh], qa[mt], 0, 0, 0); \
        }                                                                                \
        _Pragma("unroll")                                                                \
        for (int mt = 0; mt < 2; ++mt)                                                   \
        _Pragma("unroll")                                                                \
        for (int r = 0; r < 4; ++r) {                                                    \
            const int ri = mt * 16 + 4 * g + r;                                          \
            if (ri <= 16) qpeW[n15 * 17 + ri] = qa[mt][r];                               \
        }                                                                                \
        qpe0 = qpeW[n15 * 17];                                                           \
        m_r = -3.0e38f; l_r = 0.f;                                                       \
        _Pragma("unroll")                                                                \
        for (int dt = 0; dt < 4; ++dt) oacc[dt] = (f32x4){0.f, 0.f, 0.f, 0.f};           \
    } while (0)

#define STAGE_K(S, BUF)                                                                  \
    do {                                                                                 \
        _Pragma("unroll")                                                                \
        for (int j = 0; j < 2; ++j) {                                                    \
            const int cc = w * 2 + j, kh = cc >> 2, mt = cc & 3;                         \
            const short* gp = ke + (rowbase + (S) + mt * 16 + n15) * U_DIM + h * 64 + kh * 32 + g * 8; \
            async_copy16(Kc + (BUF) * 4096 + cc * 512, gp);                              \
        }                                                                                \
    } while (0)

#define LOAD_V(S)                                                                        \
    do {                                                                                 \
        const short* r0 = ve + (rowbase + (S) + 2 * sp) * U_DIM + h * 64 + dbase;        \
        vx = *(const bf16x8*)r0;                                                         \
        vy = *(const bf16x8*)(r0 + U_DIM);                                               \
    } while (0)

    // V cell store: d=dbase+i, s-pair (2sp,2sp+1): cell=(s>>5)*4+(d>>4),
    // slot=(d&15)+16*((s&31)>>3), short off j=s&7 (even -> int aligned)
#define STORE_V(BUF)                                                                     \
    do {                                                                                 \
        const int vkh = sp >> 4, vg = (sp & 15) >> 2, vj = (sp & 3) * 2;                 \
        _Pragma("unroll")                                                                \
        for (int i = 0; i < 8; ++i) {                                                    \
            const int d = dbase + i;                                                     \
            int pv = (int)((unsigned short)vx[i]) | (((int)(unsigned short)vy[i]) << 16);\
            *(int*)(Vc + (BUF) * 4096 + (vkh * 4 + (d >> 4)) * 512 + ((d & 15) + 16 * vg) * 8 + vj) = pv; \
        }                                                                                \
    } while (0)

    SETUP(tA);
    bf16x8 vx, vy;
    STAGE_K(0, 0);
    LOAD_V(0);
    STORE_V(0);

    for (int gs = 0; gs <= 16; ++gs) {
        const int cb = gs & 1, nb = cb ^ 1;
        const int s0 = (gs <= tA) ? gs * 64 : (gs - tA - 1) * 64;
        __syncthreads();
        if (gs < 16) {
            const int sn = (gs + 1 <= tA) ? (gs + 1) * 64 : (gs - tA) * 64;
            STAGE_K(sn, nb);
            LOAD_V(sn);
        }

        // ---- compute step (current phase tile, s0) ----
        {
            int cls[4];
#pragma unroll
            for (int mt = 0; mt < 4; ++mt) {
                const int slo = s0 + mt * 16;
                cls[mt] = (slo > qn + 15) ? 0 : ((slo + 31 < qn) ? 1 : 2);
            }
            f32x4 c[4];
#pragma unroll
            for (int mt = 0; mt < 4; ++mt) c[mt] = (f32x4){0.f, 0.f, 0.f, 0.f};
#pragma unroll
            for (int mt = 0; mt < 4; ++mt) {
                if (!cls[mt]) continue;
#pragma unroll
                for (int kh = 0; kh < 2; ++kh) {
                    bf16x8 ak = *(const bf16x8*)(Kc + cb * 4096 + (kh * 4 + mt) * 512 + lane * 8);
                    c[mt] = __builtin_amdgcn_mfma_f32_16x16x32_bf16(ak, Bq[kh], c[mt], 0, 0, 0);
                }
            }

            const int qg = qn + n15;
            float sc[4][4];
            float pmax = -3.0e38f;
#pragma unroll
            for (int mt = 0; mt < 4; ++mt) {
                if (cls[mt] == 0) {
#pragma unroll
                    for (int r = 0; r < 4; ++r) sc[mt][r] = -3.0e38f;
                } else if (cls[mt] == 1) {
#pragma unroll
                    for (int r = 0; r < 4; ++r) {
                        sc[mt][r] = (c[mt][r] + qpe0) * 0.125f;
                        pmax = fmaxf(pmax, sc[mt][r]);
                    }
                } else {
#pragma unroll
                    for (int r = 0; r < 4; ++r) {
                        const int sg = s0 + mt * 16 + 4 * g + r;
                        const int dlt = sg - qg;
                        if (dlt <= 0) {
                            const int ri = (dlt < -16) ? 0 : (dlt + 16);
                            sc[mt][r] = (c[mt][r] + qpeW[n15 * 17 + ri]) * 0.125f;
                            pmax = fmaxf(pmax, sc[mt][r]);
                        } else {
                            sc[mt][r] = -3.0e38f;
                        }
                    }
                }
            }
            pmax = fmaxf(pmax, __shfl_xor(pmax, 16, 64));
            pmax = fmaxf(pmax, __shfl_xor(pmax, 32, 64));
            const float mnew = fmaxf(m_r, pmax);
            const float alpha = __expf(m_r - mnew);
            float p[4][4];
            float psum = 0.f;
#pragma unroll
            for (int mt = 0; mt < 4; ++mt)
#pragma unroll
            for (int r = 0; r < 4; ++r) {
                const float pv = (cls[mt] == 0) ? 0.f : __expf(sc[mt][r] - mnew);
                p[mt][r] = pv;
                psum += pv;
            }
            psum += __shfl_xor(psum, 16, 64);
            psum += __shfl_xor(psum, 32, 64);
            l_r = l_r * alpha + psum;
            m_r = mnew;

            int pk01[4], pk23[4];
#pragma unroll
            for (int mt = 0; mt < 4; ++mt) {
                pk01[mt] = packbf(p[mt][0], p[mt][1]);
                pk23[mt] = packbf(p[mt][2], p[mt][3]);
            }
            const int srcA = ((g & 1) * 2) * 16 + n15;
            const int srcB = srcA + 16;
            const bool selHi = (g >> 1) != 0;
            float aO[4];
#pragma unroll
            for (int r = 0; r < 4; ++r) aO[r] = __shfl(alpha, 4 * g + r, 64);
#pragma unroll
            for (int dt = 0; dt < 4; ++dt)
#pragma unroll
            for (int r = 0; r < 4; ++r) oacc[dt][r] *= aO[r];
#pragma unroll
            for (int kh = 0; kh < 2; ++kh) {
                if (cls[2 * kh] == 0 && cls[2 * kh + 1] == 0) continue;
                const int a0l = __shfl(pk01[2 * kh], srcA, 64);
                const int a0h = __shfl(pk01[2 * kh + 1], srcA, 64);
                const int a1l = __shfl(pk23[2 * kh], srcA, 64);
                const int a1h = __shfl(pk23[2 * kh + 1], srcA, 64);
                const int a2l = __shfl(pk01[2 * kh], srcB, 64);
                const int a2h = __shfl(pk01[2 * kh + 1], srcB, 64);
                const int a3l = __shfl(pk23[2 * kh], srcB, 64);
                const int a3h = __shfl(pk23[2 * kh + 1], srcB, 64);
                union { int i[4]; bf16x8 v; } au;
                au.i[0] = selHi ? a0h : a0l;
                au.i[1] = selHi ? a1h : a1l;
                au.i[2] = selHi ? a2h : a2l;
                au.i[3] = selHi ? a3h : a3l;
#pragma unroll
                for (int dt = 0; dt < 4; ++dt) {
                    bf16x8 bv = *(const bf16x8*)(Vc + cb * 4096 + (kh * 4 + dt) * 512 + lane * 8);
                    oacc[dt] = __builtin_amdgcn_mfma_f32_16x16x32_bf16(au.v, bv, oacc[dt], 0, 0, 0);
                }
            }
        }

        // ---- phase switch: flush tile tA, set up tile 15-bx ----
        if (gs == tA) {
            if (g == 0)
                *(float2*)(ml + ((size_t)hb * T_SEQ + qn + n15) * 2) = make_float2(m_r, l_r);
#pragma unroll
            for (int r = 0; r < 4; ++r) {
                const float lq = __shfl(l_r, 4 * g + r, 64);
                const float linv = 1.0f / lq;
                short* dst = ao + (rowbase + qn + 4 * g + r) * U_DIM + h * 64 + n15;
#pragma unroll
                for (int dt = 0; dt < 4; ++dt)
                    dst[dt * 16] = (short)f2bf(oacc[dt][r] * linv);
            }
            SETUP(15 - bx);
        }

        if (gs < 16) STORE_V(nb);
    }

    // ---- final epilogue (tile 15-bx) ----
    if (g == 0)
        *(float2*)(ml + ((size_t)hb * T_SEQ + qn + n15) * 2) = make_float2(m_r, l_r);
#pragma unroll
    for (int r = 0; r < 4; ++r) {
        const float lq = __shfl(l_r, 4 * g + r, 64);
        const float linv = 1.0f / lq;
        short* dst = ao + (rowbase + qn + 4 * g + r) * U_DIM + h * 64 + n15;
#pragma unroll
        for (int dt = 0; dt < 4; ++dt)
            dst[dt * 16] = (short)f2bf(oacc[dt][r] * linv);
    }
#undef SETUP
#undef STAGE_K
#undef LOAD_V
#undef STORE_V
}

// ---------------------------------------------------------------------------
// band_relv: recompute 17-wide diagonal band softmax weights from (m,l),
// add rel-v term (far mass = 1 - band mass goes to pe_v[0]) into ao (RMW).
// ---------------------------------------------------------------------------
__global__ __launch_bounds__(256) void band_relv(
        const short* __restrict__ qe, const short* __restrict__ ke,
        const float* __restrict__ pe_k, const float* __restrict__ pe_v,
        const float* __restrict__ ml, short* __restrict__ ao) {
    __shared__ float pek[17 * 64];
    __shared__ float pev[17 * 64];
    const int tb = blockIdx.x, hb = blockIdx.y;
    const int h = hb >> 3, b = hb & 7;
    const int tid = threadIdx.x;
    for (int i = tid; i < 17 * 64; i += 256) {
        pek[i] = b2f((short)f2bf(pe_k[i]));   // match main kernel's bf16 rounding
        pev[i] = pe_v[i];
    }
    __syncthreads();

    const int t = tb * 64 + (tid >> 2);
    const int p = (tid & 3) * 16;
    const short* qp = qe + (size_t)(b * T_SEQ + t) * U_DIM + h * 64 + p;
    bf16x8 qa = *(const bf16x8*)qp, qb2 = *(const bf16x8*)(qp + 8);
    float qv[16];
#pragma unroll
    for (int i = 0; i < 8; ++i) { qv[i] = b2f(qa[i]); qv[8 + i] = b2f(qb2[i]); }

    float dots[17];
#pragma unroll
    for (int ri = 0; ri < 17; ++ri) {
        const int s = t - 16 + ri;
        float acc = 0.f;
        if (s >= 0) {
            const short* kp = ke + (size_t)(b * T_SEQ + s) * U_DIM + h * 64 + p;
            bf16x8 ka = *(const bf16x8*)kp, kb2 = *(const bf16x8*)(kp + 8);
#pragma unroll
            for (int d = 0; d < 8; ++d) {
                acc += qv[d] * b2f(ka[d]);
                acc += qv[8 + d] * b2f(kb2[d]);
            }
#pragma unroll
            for (int d = 0; d < 16; ++d) acc += qv[d] * pek[ri * 64 + p + d];
        }
        dots[ri] = acc;
    }
#pragma unroll
    for (int ri = 0; ri < 17; ++ri) {
        dots[ri] += __shfl_xor(dots[ri], 1, 64);
        dots[ri] += __shfl_xor(dots[ri], 2, 64);
    }

    const float2 mlv = *(const float2*)(ml + ((size_t)hb * T_SEQ + t) * 2);
    const float m = mlv.x, linv = 1.0f / mlv.y;
    float wv[17];
    float wsum = 0.f;
#pragma unroll
    for (int ri = 0; ri < 17; ++ri) {
        const int s = t - 16 + ri;
        const float wr = (s >= 0) ? __expf(dots[ri] * 0.125f - m) * linv : 0.f;
        wv[ri] = wr;
        wsum += wr;
    }
    wv[0] += 1.0f - wsum;   // far-bucket mass (all s <= t-17)

    float relv[16];
#pragma unroll
    for (int d = 0; d < 16; ++d) relv[d] = 0.f;
#pragma unroll
    for (int ri = 0; ri < 17; ++ri)
#pragma unroll
        for (int d = 0; d < 16; ++d) relv[d] += wv[ri] * pev[ri * 64 + p + d];

    short* op = ao + (size_t)(b * T_SEQ + t) * U_DIM + h * 64 + p;
    bf16x8 a0 = *(const bf16x8*)op, a1 = *(const bf16x8*)(op + 8);
    int4 o0, o1;
    o0.x = packbf(b2f(a0[0]) + relv[0],  b2f(a0[1]) + relv[1]);
    o0.y = packbf(b2f(a0[2]) + relv[2],  b2f(a0[3]) + relv[3]);
    o0.z = packbf(b2f(a0[4]) + relv[4],  b2f(a0[5]) + relv[5]);
    o0.w = packbf(b2f(a0[6]) + relv[6],  b2f(a0[7]) + relv[7]);
    o1.x = packbf(b2f(a1[0]) + relv[8],  b2f(a1[1]) + relv[9]);
    o1.y = packbf(b2f(a1[2]) + relv[10], b2f(a1[3]) + relv[11]);
    o1.z = packbf(b2f(a1[4]) + relv[12], b2f(a1[5]) + relv[13]);
    o1.w = packbf(b2f(a1[6]) + relv[14], b2f(a1[7]) + relv[15]);
    *(int4*)op = o0;
    *(int4*)(op + 8) = o1;
}

// ---------------------------------------------------------------------------
// LayerNorm: one wave per row, shuffle-only reductions.
// ---------------------------------------------------------------------------
__global__ __launch_bounds__(256) void ln_kernel(float* __restrict__ io,
                                                 const float* __restrict__ gamma,
                                                 const float* __restrict__ beta) {
    const int row = blockIdx.x * 4 + (threadIdx.x >> 6);
    const int lane = threadIdx.x & 63;
    float* rp = io + (size_t)row * 512 + lane * 8;
    float4 a = *(const float4*)rp;
    float4 c = *(const float4*)(rp + 4);
    float v[8] = {a.x, a.y, a.z, a.w, c.x, c.y, c.z, c.w};

    float s = v[0] + v[1] + v[2] + v[3] + v[4] + v[5] + v[6] + v[7];
#pragma unroll
    for (int off = 1; off < 64; off <<= 1) s += __shfl_xor(s, off, 64);
    const float mu = s * (1.0f / 512.0f);

    float sq = 0.f;
#pragma unroll
    for (int i = 0; i < 8; ++i) { v[i] -= mu; sq += v[i] * v[i]; }
#pragma unroll
    for (int off = 1; off < 64; off <<= 1) sq += __shfl_xor(sq, off, 64);
    const float rs = rsqrtf(sq * (1.0f / 512.0f) + LN_EPS);

    const float4 g0 = *(const float4*)(gamma + lane * 8);
    const float4 g1 = *(const float4*)(gamma + lane * 8 + 4);
    const float4 b0 = *(const float4*)(beta + lane * 8);
    const float4 b1 = *(const float4*)(beta + lane * 8 + 4);
    float4 o0, o1;
    o0.x = v[0] * rs * g0.x + b0.x;
    o0.y = v[1] * rs * g0.y + b0.y;
    o0.z = v[2] * rs * g0.z + b0.z;
    o0.w = v[3] * rs * g0.w + b0.w;
    o1.x = v[4] * rs * g1.x + b1.x;
    o1.y = v[5] * rs * g1.y + b1.y;
    o1.z = v[6] * rs * g1.z + b1.z;
    o1.w = v[7] * rs * g1.w + b1.w;
    *(float4*)rp = o0;
    *(float4*)(rp + 4) = o1;
}

// ---------------------------------------------------------------------------
extern "C" void kernel_launch(void* const* d_in, const int* in_sizes, int n_in,
                              void* d_out, int out_size, void* d_ws, size_t ws_size,
                              hipStream_t stream) {
    const float* q     = (const float*)d_in[0];
    const float* k     = (const float*)d_in[1];
    const float* v     = (const float*)d_in[2];
    const float* Wq    = (const float*)d_in[3];
    const float* bq    = (const float*)d_in[4];
    const float* Wk    = (const float*)d_in[5];
    const float* bk    = (const float*)d_in[6];
    const float* Wv    = (const float*)d_in[7];
    const float* bv    = (const float*)d_in[8];
    const float* Wo    = (const float*)d_in[9];
    const float* bo    = (const float*)d_in[10];
    const float* gamma = (const float*)d_in[11];
    const float* beta  = (const float*)d_in[12];
    const float* pe_k  = (const float*)d_in[13];
    const float* pe_v  = (const float*)d_in[14];
    float* out = (float*)d_out;

    char* base = (char*)d_ws;
    short* qe = (short*)(base);                          // bf16 embeddings, 8 MB each
    short* ke = (short*)(base + (((size_t)8) << 20));
    short* ve = (short*)(base + (((size_t)16) << 20));
    short* ao = (short*)(base + (((size_t)24) << 20));
    short* wt = (short*)(base + (((size_t)32) << 20));   // 4 x 512 KB bf16 Wt
    float* ml = (float*)(base + (((size_t)34) << 20));   // [64][1024][2] fp32
    short* wtq = wt, *wtk = wt + 262144, *wtv = wt + 2 * 262144, *wto = wt + 3 * 262144;

    prep_wt<<<dim3(256), 256, 0, stream>>>(Wq, Wk, Wv, Wo, wt);
    gemm_mfma<1, 0><<<dim3(64, 4, 3), 256, 0, stream>>>(
        q, k, v, wtq, wtk, wtv, bq, bk, bv, nullptr, qe, ke, ve);
    attn_mfma<<<dim3(8, 64), 256, 0, stream>>>(qe, ke, ve, pe_k, ml, ao);
    band_relv<<<dim3(16, 64), 256, 0, stream>>>(qe, ke, pe_k, pe_v, ml, ao);
    gemm_mfma<0, 1><<<dim3(64, 4, 1), 256, 0, stream>>>(
        ao, ao, ao, wto, wto, wto, bo, bo, bo, q, out, out, out);
    ln_kernel<<<dim3(2048), 256, 0, stream>>>(out, gamma, beta);
}